// Round 8
// baseline (2531.383 us; speedup 1.0000x reference)
//
#include <hip/hip_runtime.h>

typedef __attribute__((ext_vector_type(4))) float  f4;
typedef __attribute__((ext_vector_type(2))) float  f2;
typedef __attribute__((ext_vector_type(4))) unsigned short us4;
typedef __attribute__((ext_vector_type(8))) short  s8;     // bf16x8 MFMA frag
typedef __attribute__((ext_vector_type(4))) float  f32x4;  // MFMA acc

__device__ __forceinline__ unsigned short f2bf(float f) {
  unsigned u = __float_as_uint(f);
  u += 0x7fffu + ((u >> 16) & 1u);
  return (unsigned short)(u >> 16);
}
__device__ __forceinline__ float elu1(float x) { return x > 0.f ? x + 1.f : __expf(x); }
__device__ __forceinline__ float gelu_erf(float x) { return 0.5f * x * (1.f + erff(x * 0.70710678118654752f)); }

__device__ __forceinline__ void async16(const void* g, void* l) {
  __builtin_amdgcn_global_load_lds((const __attribute__((address_space(1))) void*)g,
                                   (__attribute__((address_space(3))) void*)l, 16, 0, 0);
}

// RAW barrier: no compiler-attached waitcnt drain.
__device__ __forceinline__ void rawbar() {
  asm volatile("s_barrier" ::: "memory");
}

// LDS generic pointer -> 32-bit DS address
__device__ __forceinline__ unsigned l2u(const void* p) {
  return (unsigned)(size_t)(const __attribute__((address_space(3))) char*)p;
}
// asm ds_read_b128 with compile-time immediate offset
template<int OFF>
__device__ __forceinline__ void dsr(s8& d, unsigned base) {
  asm volatile("ds_read_b128 %0, %1 offset:%2" : "=v"(d) : "v"(base), "i"(OFF));
}
template<int KB>
__device__ __forceinline__ void readA8(s8 (&af)[8], unsigned base) {
  dsr<(0 * 2 + KB) * 1024>(af[0], base);
  dsr<(1 * 2 + KB) * 1024>(af[1], base);
  dsr<(2 * 2 + KB) * 1024>(af[2], base);
  dsr<(3 * 2 + KB) * 1024>(af[3], base);
  dsr<(4 * 2 + KB) * 1024>(af[4], base);
  dsr<(5 * 2 + KB) * 1024>(af[5], base);
  dsr<(6 * 2 + KB) * 1024>(af[6], base);
  dsr<(7 * 2 + KB) * 1024>(af[7], base);
}

// ---------------- embedding: X = tok[idx] + pos, also bf16 copy ----------------
__global__ __launch_bounds__(256) void embed_kernel(
    const int* __restrict__ idx, const float* __restrict__ tok,
    const float* __restrict__ pos, float* __restrict__ X, unsigned short* __restrict__ XB)
{
  int g = blockIdx.x * 256 + threadIdx.x;
  int t = g >> 8;
  int c4 = (g & 255) * 4;
  int l = t & 2047;
  int tk = idx[t];
  f4 v = *(const f4*)(tok + (size_t)tk * 1024 + c4);
  f4 p = *(const f4*)(pos + (size_t)l * 1024 + c4);
  v += p;
  *(f4*)(X + (size_t)t * 1024 + c4) = v;
  us4 o = { f2bf(v[0]), f2bf(v[1]), f2bf(v[2]), f2bf(v[3]) };
  *(us4*)(XB + (size_t)t * 1024 + c4) = o;
}

// ---------------- f32 [K,N] -> bf16 [N,K] transpose-convert ----------------
__global__ __launch_bounds__(256) void transpose_cvt(
    const float* __restrict__ src, unsigned short* __restrict__ dst, int N, int K)
{
  __shared__ unsigned short t[64][72];
  int k0 = blockIdx.x * 64, n0 = blockIdx.y * 64;
  int tid = threadIdx.x;
#pragma unroll
  for (int i = 0; i < 4; ++i) {
    int f = tid + i * 256;
    int r = f >> 4, c4 = (f & 15) * 4;
    f4 v = *(const f4*)(src + (size_t)(k0 + r) * N + n0 + c4);
    us4 o = { f2bf(v[0]), f2bf(v[1]), f2bf(v[2]), f2bf(v[3]) };
    *(us4*)&t[r][c4] = o;
  }
  __syncthreads();
#pragma unroll
  for (int i = 0; i < 4; ++i) {
    int f = tid + i * 256;
    int nr = f >> 4, kc4 = (f & 15) * 4;
    us4 o = { t[kc4 + 0][nr], t[kc4 + 1][nr], t[kc4 + 2][nr], t[kc4 + 3][nr] };
    *(us4*)(dst + (size_t)(n0 + nr) * K + k0 + kc4) = o;
  }
}

// ---------------- old 128x128 bf16 MFMA GEMM (kept for QKV + fallback) --------
template<int EPI, int BF32>
__global__ __launch_bounds__(256) void gemm_bt(
    const unsigned short* __restrict__ A, const unsigned short* __restrict__ Bt,
    const float* __restrict__ Bf, const float* __restrict__ bias,
    void* __restrict__ Cv, int M, int N, int K, int mtiles)
{
  __shared__ unsigned short As[128 * 32];
  __shared__ unsigned short Bs[128 * 32];
  int bid = blockIdx.x;
  int mt = bid % mtiles, nt = bid / mtiles;
  int m0 = mt * 128, n0 = nt * 128;
  int tid = threadIdx.x, lane = tid & 63, w = tid >> 6;
  int wm = (w & 1) * 64, wn = (w >> 1) * 64;

  int c0 = w * 128 + lane, c1 = c0 + 64;
  size_t aO0 = (size_t)(m0 + (c0 >> 2)) * K + (size_t)((c0 & 3) * 8);
  size_t aO1 = (size_t)(m0 + (c1 >> 2)) * K + (size_t)((c1 & 3) * 8);
  size_t bO0 = (size_t)(n0 + (c0 >> 2)) * K + (size_t)((c0 & 3) * 8);
  size_t bO1 = (size_t)(n0 + (c1 >> 2)) * K + (size_t)((c1 & 3) * 8);
  unsigned short* lA0 = As + (w * 128) * 8;
  unsigned short* lA1 = As + (w * 128 + 64) * 8;
  unsigned short* lB0 = Bs + (w * 128) * 8;
  unsigned short* lB1 = Bs + (w * 128 + 64) * 8;

  f32x4 acc[4][4];
  f32x4 zz = {0.f, 0.f, 0.f, 0.f};
#pragma unroll
  for (int i = 0; i < 4; ++i)
#pragma unroll
    for (int j = 0; j < 4; ++j) acc[i][j] = zz;

  int rr = lane & 15, kh = (lane >> 4) * 8;
  const unsigned short* Ar = As + (wm + rr) * 32 + kh;
  const unsigned short* Br = Bs + (wn + rr) * 32 + kh;

  for (int k0 = 0; k0 < K; k0 += 32) {
    async16(A + aO0 + k0, lA0);
    async16(A + aO1 + k0, lA1);
    if constexpr (!BF32) {
      async16(Bt + bO0 + k0, lB0);
      async16(Bt + bO1 + k0, lB1);
    } else {
#pragma unroll
      for (int i = 0; i < 4; ++i) {
        int f = tid + i * 256;
        int kr = f >> 5, c4 = (f & 31) * 4;
        f4 v = *(const f4*)(Bf + (size_t)(k0 + kr) * N + n0 + c4);
#pragma unroll
        for (int e = 0; e < 4; ++e) Bs[(c4 + e) * 32 + kr] = f2bf(v[e]);
      }
    }
    __syncthreads();
    s8 af[4], bfr[4];
#pragma unroll
    for (int mi = 0; mi < 4; ++mi) af[mi] = *(const s8*)(Ar + mi * 512);
#pragma unroll
    for (int ni = 0; ni < 4; ++ni) bfr[ni] = *(const s8*)(Br + ni * 512);
#pragma unroll
    for (int mi = 0; mi < 4; ++mi)
#pragma unroll
      for (int ni = 0; ni < 4; ++ni)
        acc[mi][ni] = __builtin_amdgcn_mfma_f32_16x16x32_bf16(af[mi], bfr[ni], acc[mi][ni], 0, 0, 0);
    __syncthreads();
  }

  int cr = (lane >> 4) * 4;
#pragma unroll
  for (int mi = 0; mi < 4; ++mi) {
#pragma unroll
    for (int ni = 0; ni < 4; ++ni) {
      int gc = n0 + wn + ni * 16 + rr;
      float bv = (EPI > 0) ? bias[gc] : 0.f;
#pragma unroll
      for (int r = 0; r < 4; ++r) {
        int gr = m0 + wm + mi * 16 + cr + r;
        float v = acc[mi][ni][r] + bv;
        if constexpr (EPI == 1) {
          ((unsigned short*)Cv)[(size_t)gr * N + gc] = f2bf(gelu_erf(v));
        } else {
          ((float*)Cv)[(size_t)gr * N + gc] = v;
        }
      }
    }
  }
}

// ======== 256x256 software-pipelined 8-phase bf16 GEMM (r7, kept for W1) ======
template<int RA, int RDKB, int RDNH, int ACCN, typename STG>
__device__ __forceinline__ void phaseX(
    unsigned ArdB, unsigned BrdB,
    s8 (&afDst)[8], s8 (&bfDst)[2],
    const s8 (&afUse)[8], const s8 (&bfUse)[2],
    f32x4 (&acc)[8][4], STG stg)
{
  dsr<((RDNH * 2 + 0) * 2 + RDKB) * 1024>(bfDst[0], BrdB);
  dsr<((RDNH * 2 + 1) * 2 + RDKB) * 1024>(bfDst[1], BrdB);
  if constexpr (RA) readA8<RDKB>(afDst, ArdB);
  stg();
  asm volatile("s_waitcnt vmcnt(6)" ::: "memory");
  rawbar();
  if constexpr (RA) asm volatile("s_waitcnt lgkmcnt(10)" ::: "memory");
  else              asm volatile("s_waitcnt lgkmcnt(2)" ::: "memory");
  __builtin_amdgcn_sched_barrier(0);
  __builtin_amdgcn_s_setprio(1);
#pragma unroll
  for (int f = 0; f < 8; ++f) {
    acc[f][ACCN * 2 + 0] =
        __builtin_amdgcn_mfma_f32_16x16x32_bf16(afUse[f], bfUse[0], acc[f][ACCN * 2 + 0], 0, 0, 0);
    acc[f][ACCN * 2 + 1] =
        __builtin_amdgcn_mfma_f32_16x16x32_bf16(afUse[f], bfUse[1], acc[f][ACCN * 2 + 1], 0, 0, 0);
  }
  __builtin_amdgcn_s_setprio(0);
  __builtin_amdgcn_sched_barrier(0);
}

template<int EPI>  // 1 = bias+GELU->bf16, 2 = bias->f32
__global__ __launch_bounds__(512, 2) void gemm256(
    const unsigned short* __restrict__ A, const unsigned short* __restrict__ Bt,
    const float* __restrict__ bias, void* __restrict__ Cv,
    int M, int N, int K, int mtiles)
{
  __shared__ __align__(16) char A0r[32768];
  __shared__ __align__(16) char B0r[32768];
  __shared__ __align__(16) char A1r[32768];
  __shared__ __align__(16) char B1r[32768];

  const int tid = threadIdx.x, lane = tid & 63, w = tid >> 6;
  const int wm = w >> 2, wn = w & 3;
  const int NT = K >> 6;

  int nwg = gridDim.x, orig = blockIdx.x;
  int q = nwg >> 3, r = nwg & 7;
  int xcd = orig & 7, lin = orig >> 3;
  int swz = (xcd < r ? xcd * (q + 1) : r * (q + 1) + (xcd - r) * q) + lin;
  int mt = swz % mtiles, nt = swz / mtiles;
  int m0 = mt * 256, n0 = nt * 256;

  const size_t klane8 = (size_t)((lane >> 4) << 3);
  const size_t arow0 = (size_t)(m0 + w * 32 + (lane & 15)) * K;
  const size_t arow1 = arow0 + (size_t)16 * K;
  const size_t brow0 = (size_t)(n0 + w * 32 + (lane & 15)) * K;
  const size_t brow1 = brow0 + (size_t)16 * K;

  auto stgA = [&](char* reg, int kt, int kb) {
    int ktc = kt < NT ? kt : NT - 1;
    size_t kk = (size_t)ktc * 64 + (size_t)(kb * 32) + klane8;
    char* d = reg + w * 4096 + kb * 1024;
    async16(A + arow0 + kk, d);
    async16(A + arow1 + kk, d + 2048);
  };
  auto stgB = [&](char* reg, int kt, int kb) {
    int ktc = kt < NT ? kt : NT - 1;
    size_t kk = (size_t)ktc * 64 + (size_t)(kb * 32) + klane8;
    char* d = reg + w * 4096 + kb * 1024;
    async16(Bt + brow0 + kk, d);
    async16(Bt + brow1 + kk, d + 2048);
  };

  const unsigned AB0 = l2u(A0r + wm * 16384 + lane * 16);
  const unsigned BB0 = l2u(B0r + wn * 8192 + lane * 16);
  const unsigned AB1 = l2u(A1r + wm * 16384 + lane * 16);
  const unsigned BB1 = l2u(B1r + wn * 8192 + lane * 16);

  f32x4 acc[8][4];
  f32x4 zz = {0.f, 0.f, 0.f, 0.f};
#pragma unroll
  for (int i = 0; i < 8; ++i)
#pragma unroll
    for (int j = 0; j < 4; ++j) acc[i][j] = zz;
  s8 afA[8], afB[8], bfA[2], bfB[2];

  stgA(A0r, 0, 0); stgB(B0r, 0, 0);
  stgA(A0r, 0, 1); stgB(B0r, 0, 1);
  stgA(A1r, 1, 0); stgB(B1r, 1, 0);
  asm volatile("s_waitcnt vmcnt(8)" ::: "memory");
  rawbar();
  readA8<0>(afA, AB0);
  dsr<0>(bfA[0], BB0);
  dsr<2048>(bfA[1], BB0);

  for (int te = 0; te < NT; te += 2) {
    phaseX<0, 0, 1, 0>(AB0, BB0, afA, bfB, afA, bfA, acc, [&] { stgA(A1r, te + 1, 1); });
    phaseX<1, 1, 1, 1>(AB0, BB0, afB, bfA, afA, bfB, acc, [&] { stgB(B1r, te + 1, 1); });
    phaseX<0, 1, 0, 1>(AB0, BB0, afA, bfB, afB, bfA, acc, [&] { stgA(A0r, te + 2, 0); });
    phaseX<1, 0, 0, 0>(AB1, BB1, afA, bfA, afB, bfB, acc, [&] { stgB(B0r, te + 2, 0); });
    phaseX<0, 0, 1, 0>(AB1, BB1, afA, bfB, afA, bfA, acc, [&] { stgA(A0r, te + 2, 1); });
    phaseX<1, 1, 1, 1>(AB1, BB1, afB, bfA, afA, bfB, acc, [&] { stgB(B0r, te + 2, 1); });
    phaseX<0, 1, 0, 1>(AB1, BB1, afA, bfB, afB, bfA, acc, [&] { stgA(A1r, te + 3, 0); });
    phaseX<1, 0, 0, 0>(AB0, BB0, afA, bfA, afB, bfB, acc, [&] { stgB(B1r, te + 3, 0); });
  }

  asm volatile("s_waitcnt vmcnt(0) lgkmcnt(0)" ::: "memory");
  __builtin_amdgcn_sched_barrier(0);

  int rr = lane & 15, cr = (lane >> 4) * 4;
#pragma unroll
  for (int f = 0; f < 8; ++f) {
#pragma unroll
    for (int ni = 0; ni < 4; ++ni) {
      int gc = n0 + wn * 64 + ni * 16 + rr;
      float bv = bias[gc];
#pragma unroll
      for (int rg = 0; rg < 4; ++rg) {
        int gr = m0 + wm * 128 + f * 16 + cr + rg;
        float v = acc[f][ni][rg] + bv;
        if constexpr (EPI == 1) {
          ((unsigned short*)Cv)[(size_t)gr * N + gc] = f2bf(gelu_erf(v));
        } else {
          ((float*)Cv)[(size_t)gr * N + gc] = v;
        }
      }
    }
  }
}

// ======== 128x128 bf16 GEMM, 4 waves, 64KB LDS -> 2 BLOCKS/CU (TLP test) ======
// Two independent barrier domains per CU: while one block sits in its
// barrier/waitcnt stall, the other block's waves feed the MFMA pipe (m114
// mechanism). Inner loop = r7 machinery scaled down: fragment-contiguous LDS
// (0 conflicts), asm ds_read, raw barriers, counted vmcnt(8)/phase,
// lgkmcnt(0)+sched_barrier before MFMA cluster, setprio around it.
// Ring (audited): per phase stages A+B of one kb for tile t+2 (depth-2 dbuf);
// every region write-issue is >=1 barrier after all its readers' issues (WAR);
// vmcnt(8) leaves only the 2 newest phases' loads outstanding, certifying the
// region read next phase (RAW). Tail via kt clamp keeps counts uniform.
template<int KB, typename STG>
__device__ __forceinline__ void phaseY(
    unsigned AB, unsigned BB, f32x4 (&acc)[4][4], STG stg)
{
  s8 a0, a1, a2, a3, b0, b1, b2, b3;
  dsr<(0 * 2 + KB) * 1024>(a0, AB);
  dsr<(1 * 2 + KB) * 1024>(a1, AB);
  dsr<(2 * 2 + KB) * 1024>(a2, AB);
  dsr<(3 * 2 + KB) * 1024>(a3, AB);
  dsr<(0 * 2 + KB) * 1024>(b0, BB);
  dsr<(1 * 2 + KB) * 1024>(b1, BB);
  dsr<(2 * 2 + KB) * 1024>(b2, BB);
  dsr<(3 * 2 + KB) * 1024>(b3, BB);
  stg();
  asm volatile("s_waitcnt vmcnt(8)" ::: "memory");
  rawbar();
  asm volatile("s_waitcnt lgkmcnt(0)" ::: "memory");
  __builtin_amdgcn_sched_barrier(0);
  __builtin_amdgcn_s_setprio(1);
  acc[0][0] = __builtin_amdgcn_mfma_f32_16x16x32_bf16(a0, b0, acc[0][0], 0, 0, 0);
  acc[1][0] = __builtin_amdgcn_mfma_f32_16x16x32_bf16(a1, b0, acc[1][0], 0, 0, 0);
  acc[2][0] = __builtin_amdgcn_mfma_f32_16x16x32_bf16(a2, b0, acc[2][0], 0, 0, 0);
  acc[3][0] = __builtin_amdgcn_mfma_f32_16x16x32_bf16(a3, b0, acc[3][0], 0, 0, 0);
  acc[0][1] = __builtin_amdgcn_mfma_f32_16x16x32_bf16(a0, b1, acc[0][1], 0, 0, 0);
  acc[1][1] = __builtin_amdgcn_mfma_f32_16x16x32_bf16(a1, b1, acc[1][1], 0, 0, 0);
  acc[2][1] = __builtin_amdgcn_mfma_f32_16x16x32_bf16(a2, b1, acc[2][1], 0, 0, 0);
  acc[3][1] = __builtin_amdgcn_mfma_f32_16x16x32_bf16(a3, b1, acc[3][1], 0, 0, 0);
  acc[0][2] = __builtin_amdgcn_mfma_f32_16x16x32_bf16(a0, b2, acc[0][2], 0, 0, 0);
  acc[1][2] = __builtin_amdgcn_mfma_f32_16x16x32_bf16(a1, b2, acc[1][2], 0, 0, 0);
  acc[2][2] = __builtin_amdgcn_mfma_f32_16x16x32_bf16(a2, b2, acc[2][2], 0, 0, 0);
  acc[3][2] = __builtin_amdgcn_mfma_f32_16x16x32_bf16(a3, b2, acc[3][2], 0, 0, 0);
  acc[0][3] = __builtin_amdgcn_mfma_f32_16x16x32_bf16(a0, b3, acc[0][3], 0, 0, 0);
  acc[1][3] = __builtin_amdgcn_mfma_f32_16x16x32_bf16(a1, b3, acc[1][3], 0, 0, 0);
  acc[2][3] = __builtin_amdgcn_mfma_f32_16x16x32_bf16(a2, b3, acc[2][3], 0, 0, 0);
  acc[3][3] = __builtin_amdgcn_mfma_f32_16x16x32_bf16(a3, b3, acc[3][3], 0, 0, 0);
  __builtin_amdgcn_s_setprio(0);
  __builtin_amdgcn_sched_barrier(0);
  rawbar();
}

template<int EPI>  // 1 = bias+GELU->bf16, 2 = bias->f32
__global__ __launch_bounds__(256, 2) void gemm128(
    const unsigned short* __restrict__ A, const unsigned short* __restrict__ Bt,
    const float* __restrict__ bias, void* __restrict__ Cv,
    int M, int N, int K, int mtiles)
{
  __shared__ __align__(16) char A0r[16384];
  __shared__ __align__(16) char B0r[16384];
  __shared__ __align__(16) char A1r[16384];
  __shared__ __align__(16) char B1r[16384];

  const int tid = threadIdx.x, lane = tid & 63, w = tid >> 6;
  const int wm = w >> 1, wn = w & 1;
  const int NT = K >> 6;

  // bijective XCD swizzle (m204)
  int nwg = gridDim.x, orig = blockIdx.x;
  int q = nwg >> 3, r = nwg & 7;
  int xcd = orig & 7, lin = orig >> 3;
  int swz = (xcd < r ? xcd * (q + 1) : r * (q + 1) + (xcd - r) * q) + lin;
  int mt = swz % mtiles, nt = swz / mtiles;
  int m0 = mt * 128, n0 = nt * 128;

  // staging: LDS block (half, sub, kb) = 1KB holding rows half*64+sub*16+(l&15),
  // k-chunk kb*32+(l>>4)*8. Per stg call: 4 waves x 2 instr cover all 8 blocks
  // of one (region, kb). Per-lane global source, wave-uniform LDS dest.
  const int lrow = lane & 15;
  const size_t lcol = (size_t)((lane >> 4) << 3);

  auto stgA = [&](char* reg, int kt, int kb) {
    int ktc = kt < NT ? kt : NT - 1;
    size_t cb = (size_t)ktc * 64 + (size_t)(kb * 32) + lcol;
#pragma unroll
    for (int j = 0; j < 2; ++j) {
      int idx = w * 2 + j;
      int half = idx >> 2, sub = idx & 3;
      size_t row = (size_t)(m0 + half * 64 + sub * 16 + lrow);
      char* d = reg + half * 8192 + (sub * 2 + kb) * 1024;
      async16(A + row * K + cb, d);
    }
  };
  auto stgB = [&](char* reg, int kt, int kb) {
    int ktc = kt < NT ? kt : NT - 1;
    size_t cb = (size_t)ktc * 64 + (size_t)(kb * 32) + lcol;
#pragma unroll
    for (int j = 0; j < 2; ++j) {
      int idx = w * 2 + j;
      int half = idx >> 2, sub = idx & 3;
      size_t row = (size_t)(n0 + half * 64 + sub * 16 + lrow);
      char* d = reg + half * 8192 + (sub * 2 + kb) * 1024;
      async16(Bt + row * K + cb, d);
    }
  };

  // fragment read bases: A frag (mi,kb) at wm*8192 + (mi*2+kb)*1024
  const unsigned AB0 = l2u(A0r + wm * 8192 + lane * 16);
  const unsigned BB0 = l2u(B0r + wn * 8192 + lane * 16);
  const unsigned AB1 = l2u(A1r + wm * 8192 + lane * 16);
  const unsigned BB1 = l2u(B1r + wn * 8192 + lane * 16);

  f32x4 acc[4][4];
  f32x4 zz = {0.f, 0.f, 0.f, 0.f};
#pragma unroll
  for (int i = 0; i < 4; ++i)
#pragma unroll
    for (int j = 0; j < 4; ++j) acc[i][j] = zz;

  // prologue: tile0 full + tile1 kb0 (12 loads); vmcnt(8) certifies tile0.kb0
  stgA(A0r, 0, 0); stgB(B0r, 0, 0);
  stgA(A0r, 0, 1); stgB(B0r, 0, 1);
  stgA(A1r, 1, 0); stgB(B1r, 1, 0);
  asm volatile("s_waitcnt vmcnt(8)" ::: "memory");
  rawbar();

  for (int te = 0; te < NT; te += 2) {
    // tile te (buf0)
    phaseY<0>(AB0, BB0, acc, [&] { stgA(A1r, te + 1, 1); stgB(B1r, te + 1, 1); });
    phaseY<1>(AB0, BB0, acc, [&] { stgA(A0r, te + 2, 0); stgB(B0r, te + 2, 0); });
    // tile te+1 (buf1)
    phaseY<0>(AB1, BB1, acc, [&] { stgA(A0r, te + 2, 1); stgB(B0r, te + 2, 1); });
    phaseY<1>(AB1, BB1, acc, [&] { stgA(A1r, te + 3, 0); stgB(B1r, te + 3, 0); });
  }

  asm volatile("s_waitcnt vmcnt(0) lgkmcnt(0)" ::: "memory");
  __builtin_amdgcn_sched_barrier(0);

  // epilogue: C/D map col=lane&15, row=(lane>>4)*4+reg
  int rr = lane & 15, cr = (lane >> 4) * 4;
#pragma unroll
  for (int mi = 0; mi < 4; ++mi) {
#pragma unroll
    for (int ni = 0; ni < 4; ++ni) {
      int gc = n0 + wn * 64 + ni * 16 + rr;
      float bv = bias[gc];
#pragma unroll
      for (int rg = 0; rg < 4; ++rg) {
        int gr = m0 + wm * 64 + mi * 16 + cr + rg;
        float v = acc[mi][ni][rg] + bv;
        if constexpr (EPI == 1) {
          ((unsigned short*)Cv)[(size_t)gr * N + gc] = f2bf(gelu_erf(v));
        } else {
          ((float*)Cv)[(size_t)gr * N + gc] = v;
        }
      }
    }
  }
}

// ---------------- per-chunk K^T V and K sums ----------------
__global__ __launch_bounds__(256) void chunk_sums(
    const float* __restrict__ QKV, float* __restrict__ KVc, float* __restrict__ Ksum)
{
  __shared__ float Ks[64][68], Vs[64][68];
  int blk = blockIdx.x, t0 = blk * 64, tid = threadIdx.x;
#pragma unroll
  for (int i = 0; i < 4; ++i) {
    int f = tid + i * 256;
    int r = f >> 4, c4 = (f & 15) * 4;
    const float* s = QKV + (size_t)(t0 + r) * 256;
    f4 k = *(const f4*)(s + 64 + c4);
    f4 v = *(const f4*)(s + 128 + c4);
#pragma unroll
    for (int e = 0; e < 4; ++e) { Ks[r][c4 + e] = elu1(k[e]); Vs[r][c4 + e] = v[e]; }
  }
  __syncthreads();
  int i0 = tid >> 2, jb = (tid & 3) * 16;
  f4 a0 = {0,0,0,0}, a1 = {0,0,0,0}, a2 = {0,0,0,0}, a3 = {0,0,0,0};
  for (int t = 0; t < 64; ++t) {
    float kk = Ks[t][i0];
    a0 += kk * (*(const f4*)&Vs[t][jb]);
    a1 += kk * (*(const f4*)&Vs[t][jb + 4]);
    a2 += kk * (*(const f4*)&Vs[t][jb + 8]);
    a3 += kk * (*(const f4*)&Vs[t][jb + 12]);
  }
  float* d = KVc + (size_t)blk * 4096 + i0 * 64 + jb;
  *(f4*)(d) = a0; *(f4*)(d + 4) = a1; *(f4*)(d + 8) = a2; *(f4*)(d + 12) = a3;
  if (tid < 64) {
    float s = 0.f;
    for (int t = 0; t < 64; ++t) s += Ks[t][tid];
    Ksum[(size_t)blk * 64 + tid] = s;
  }
}

// ---------------- exclusive prefix of chunk states ----------------
__global__ __launch_bounds__(256) void prefix_state(
    const float* __restrict__ KVc, const float* __restrict__ Ksum,
    float* __restrict__ KVp, float* __restrict__ Ksump)
{
  int b = blockIdx.x >> 3, seg = blockIdx.x & 7;
  int e = seg * 512 + threadIdx.x * 2;
  f2 run = {0.f, 0.f};
#pragma unroll
  for (int c = 0; c < 32; ++c) {
    size_t base = ((size_t)b * 32 + c) * 4096 + e;
    *(f2*)(KVp + base) = run;
    run += *(const f2*)(KVc + base);
  }
  if (seg == 0 && threadIdx.x < 64) {
    float rs = 0.f; int i = threadIdx.x;
#pragma unroll
    for (int c = 0; c < 32; ++c) {
      size_t base = ((size_t)b * 32 + c) * 64 + i;
      Ksump[base] = rs;
      rs += Ksum[base];
    }
  }
}

// ---------------- per-chunk normalized attention coefficients ----------------
__global__ __launch_bounds__(256) void attn_ns(
    const float* __restrict__ QKV, const float* __restrict__ KVp,
    const float* __restrict__ Ksump, float* __restrict__ NsG)
{
  __shared__ float Qs[64][68], Ks[64][68], Vs[64][68], Ss[64][68], Ps[64][68];
  __shared__ float ksps[64];
  int blk = blockIdx.x, t0 = blk * 64, tid = threadIdx.x;
#pragma unroll
  for (int i = 0; i < 4; ++i) {
    int f = tid + i * 256;
    int r = f >> 4, c4 = (f & 15) * 4;
    const float* s = QKV + (size_t)(t0 + r) * 256;
    f4 q = *(const f4*)(s + c4);
    f4 k = *(const f4*)(s + 64 + c4);
    f4 v = *(const f4*)(s + 128 + c4);
    f4 p = *(const f4*)(KVp + (size_t)blk * 4096 + r * 64 + c4);
#pragma unroll
    for (int e = 0; e < 4; ++e) {
      Qs[r][c4 + e] = elu1(q[e]); Ks[r][c4 + e] = elu1(k[e]);
      Vs[r][c4 + e] = v[e];       Ps[r][c4 + e] = p[e];
    }
  }
  if (tid < 64) ksps[tid] = Ksump[(size_t)blk * 64 + tid];
  __syncthreads();
  int tq = tid >> 2, jb = (tid & 3) * 16;
#pragma unroll
  for (int jj = 0; jj < 16; ++jj) {
    int tk = jb + jj;
    float s = 0.f;
    if (tk <= tq) {
#pragma unroll
      for (int k4 = 0; k4 < 16; ++k4) {
        f4 q = *(const f4*)&Qs[tq][k4 * 4];
        f4 k = *(const f4*)&Ks[tk][k4 * 4];
        s += q[0] * k[0] + q[1] * k[1] + q[2] * k[2] + q[3] * k[3];
      }
    }
    Ss[tq][tk] = s;
  }
  __syncthreads();
  f4 a0 = {0,0,0,0}, a1 = {0,0,0,0}, a2 = {0,0,0,0}, a3 = {0,0,0,0};
  for (int t = 0; t < 64; ++t) {
    float s = Ss[tq][t];
    a0 += s * (*(const f4*)&Vs[t][jb]);
    a1 += s * (*(const f4*)&Vs[t][jb + 4]);
    a2 += s * (*(const f4*)&Vs[t][jb + 8]);
    a3 += s * (*(const f4*)&Vs[t][jb + 12]);
  }
  for (int k = 0; k < 64; ++k) {
    float q = Qs[tq][k];
    a0 += q * (*(const f4*)&Ps[k][jb]);
    a1 += q * (*(const f4*)&Ps[k][jb + 4]);
    a2 += q * (*(const f4*)&Ps[k][jb + 8]);
    a3 += q * (*(const f4*)&Ps[k][jb + 12]);
  }
  float den = 0.f;
  for (int t = 0; t < 64; ++t) den += Ss[tq][t];
  for (int k = 0; k < 64; ++k) den += Qs[tq][k] * ksps[k];
  float inv = 1.f / (den + 1e-6f);
  float* d = NsG + (size_t)(t0 + tq) * 64 + jb;
  *(f4*)(d)      = a0 * inv;
  *(f4*)(d + 4)  = a1 * inv;
  *(f4*)(d + 8)  = a2 * inv;
  *(f4*)(d + 12) = a3 * inv;
}

// ---------------- attn @ Wo + residual into X ----------------
__global__ __launch_bounds__(256) void attn_apply(
    const float* __restrict__ NsG, const float* __restrict__ Wo, float* __restrict__ X)
{
  __shared__ float Ns[64][68];
  __shared__ float Wt[64][260];
  int chunk = blockIdx.x >> 2, dg = blockIdx.x & 3;
  int t0 = chunk * 64, d0 = dg * 256, tid = threadIdx.x;
#pragma unroll
  for (int i = 0; i < 4; ++i) {
    int f = tid + i * 256;
    int r = f >> 4, c4 = (f & 15) * 4;
    *(f4*)&Ns[r][c4] = *(const f4*)(NsG + (size_t)(t0 + r) * 64 + c4);
  }
#pragma unroll
  for (int i = 0; i < 16; ++i) {
    int f = tid + i * 256;
    int r = f >> 6, c4 = (f & 63) * 4;
    *(f4*)&Wt[r][c4] = *(const f4*)(Wo + (size_t)r * 1024 + d0 + c4);
  }
  __syncthreads();
  int w = tid >> 6, lane = tid & 63;
  for (int ts = 0; ts < 16; ++ts) {
    int t = w * 16 + ts;
    float a0 = 0.f, a1 = 0.f, a2 = 0.f, a3 = 0.f;
#pragma unroll
    for (int j = 0; j < 64; ++j) {
      float nv = Ns[t][j];
      a0 += nv * Wt[j][lane];
      a1 += nv * Wt[j][64 + lane];
      a2 += nv * Wt[j][128 + lane];
      a3 += nv * Wt[j][192 + lane];
    }
    size_t o = (size_t)(t0 + t) * 1024 + d0 + lane;
    X[o]       += a0;
    X[o + 64]  += a1;
    X[o + 128] += a2;
    X[o + 192] += a3;
  }
}

// ---------------- layernorm over D=1024, writes f32 + bf16 ----------------
__global__ __launch_bounds__(256) void layernorm_kernel(
    float* __restrict__ X, unsigned short* __restrict__ XB,
    const float* __restrict__ g, const float* __restrict__ b)
{
  int t = blockIdx.x * 4 + (threadIdx.x >> 6);
  int lane = threadIdx.x & 63;
  float* row = X + (size_t)t * 1024;
  f4 v[4];
  float s = 0.f, s2 = 0.f;
#pragma unroll
  for (int i = 0; i < 4; ++i) {
    v[i] = *(const f4*)(row + (i * 64 + lane) * 4);
#pragma unroll
    for (int e = 0; e < 4; ++e) { s += v[i][e]; s2 += v[i][e] * v[i][e]; }
  }
#pragma unroll
  for (int off = 32; off > 0; off >>= 1) {
    s  += __shfl_xor(s, off, 64);
    s2 += __shfl_xor(s2, off, 64);
  }
  float mean = s * (1.f / 1024.f);
  float var = s2 * (1.f / 1024.f) - mean * mean;
  float rstd = rsqrtf(var + 1e-5f);
#pragma unroll
  for (int i = 0; i < 4; ++i) {
    int d = (i * 64 + lane) * 4;
    f4 gv = *(const f4*)(g + d);
    f4 bv = *(const f4*)(b + d);
    f4 y;
#pragma unroll
    for (int e = 0; e < 4; ++e) y[e] = (v[i][e] - mean) * rstd * gv[e] + bv[e];
    *(f4*)(row + d) = y;
    us4 o = { f2bf(y[0]), f2bf(y[1]), f2bf(y[2]), f2bf(y[3]) };
    *(us4*)(XB + (size_t)t * 1024 + d) = o;
  }
}

extern "C" void kernel_launch(void* const* d_in, const int* in_sizes, int n_in,
                              void* d_out, int out_size, void* d_ws, size_t ws_size,
                              hipStream_t stream) {
  (void)in_sizes; (void)n_in; (void)out_size;
  const int*   idx = (const int*)d_in[0];
  const float* tok = (const float*)d_in[1];
  const float* pos = (const float*)d_in[2];
  const float* Wq  = (const float*)d_in[3];
  const float* Wk  = (const float*)d_in[4];
  const float* Wv  = (const float*)d_in[5];
  const float* Wo  = (const float*)d_in[6];
  const float* ng  = (const float*)d_in[7];
  const float* nb  = (const float*)d_in[8];
  const float* ong = (const float*)d_in[9];
  const float* onb = (const float*)d_in[10];
  const float* W1  = (const float*)d_in[11];
  const float* b1  = (const float*)d_in[12];
  const float* W2  = (const float*)d_in[13];
  const float* b2  = (const float*)d_in[14];
  float* out = (float*)d_out;
  char* ws = (char*)d_ws;

  float* X            = (float*)(ws + 0);
  unsigned short* XB  = (unsigned short*)(ws + 16777216);
  unsigned short* QT0 = (unsigned short*)(ws + 25165824);
  unsigned short* QT1 = (unsigned short*)(ws + 25690112);
  float* QKVB         = (float*)(ws + 26214400);
  float* KVC          = (float*)(ws + 30408704);
  float* KSUM         = (float*)(ws + 31457280);
  float* KVP          = (float*)(ws + 31490048);
  float* KSP          = (float*)(ws + 32538624);
  unsigned short* W1T = (unsigned short*)(ws + 32571392);
  unsigned short* H   = (unsigned short*)(ws + 40960000);
  unsigned short* W2T = (unsigned short*)(ws + 74514432);
  float* NSG = KVC;  // reuse: KVC dead after prefix_state
  bool bigws = ws_size >= 336658432ull;

  hipMemsetAsync(QT0, 0, 524288, stream);
  hipMemsetAsync(QT1, 0, 524288, stream);
  transpose_cvt<<<dim3(16, 1), 256, 0, stream>>>(Wq,          QT0,              64, 1024);
  transpose_cvt<<<dim3(16, 1), 256, 0, stream>>>(Wk,          QT0 + 64 * 1024,  64, 1024);
  transpose_cvt<<<dim3(16, 1), 256, 0, stream>>>(Wv,          QT0 + 128 * 1024, 64, 1024);
  transpose_cvt<<<dim3(16, 1), 256, 0, stream>>>(Wq + 65536,  QT1,              64, 1024);
  transpose_cvt<<<dim3(16, 1), 256, 0, stream>>>(Wk + 65536,  QT1 + 64 * 1024,  64, 1024);
  transpose_cvt<<<dim3(16, 1), 256, 0, stream>>>(Wv + 65536,  QT1 + 128 * 1024, 64, 1024);
  transpose_cvt<<<dim3(16, 64), 256, 0, stream>>>(W1, W1T, 4096, 1024);
  if (bigws)
    transpose_cvt<<<dim3(64, 500), 256, 0, stream>>>(W2, W2T, 32000, 4096);

  embed_kernel<<<4096, 256, 0, stream>>>(idx, tok, pos, X, XB);

  for (int layer = 0; layer < 2; ++layer) {
    const unsigned short* QT = layer ? QT1 : QT0;
    gemm_bt<0, 0><<<64, 256, 0, stream>>>(XB, QT, nullptr, nullptr, QKVB, 4096, 256, 1024, 32);
    chunk_sums<<<64, 256, 0, stream>>>(QKVB, KVC, KSUM);
    prefix_state<<<16, 256, 0, stream>>>(KVC, KSUM, KVP, KSP);
    attn_ns<<<64, 256, 0, stream>>>(QKVB, KVP, KSP, NSG);
    attn_apply<<<256, 256, 0, stream>>>(NSG, Wo + (size_t)layer * 65536, X);
    layernorm_kernel<<<1024, 256, 0, stream>>>(X, XB, ng + layer * 1024, nb + layer * 1024);
  }
  layernorm_kernel<<<1024, 256, 0, stream>>>(X, XB, ong, onb);

  gemm256<1><<<256, 512, 0, stream>>>(XB, W1T, b1, H, 4096, 4096, 1024, 16);
  if (bigws)
    gemm128<2><<<8000, 256, 0, stream>>>(H, W2T, b2, out, 4096, 32000, 4096, 32);
  else
    gemm_bt<2, 1><<<8000, 256, 0, stream>>>(H, nullptr, W2, b2, out, 4096, 32000, 4096, 32);
}

// Round 9
// 1701.982 us; speedup vs baseline: 1.4873x; 1.4873x over previous
//
#include <hip/hip_runtime.h>

typedef __attribute__((ext_vector_type(4))) float  f4;
typedef __attribute__((ext_vector_type(2))) float  f2;
typedef __attribute__((ext_vector_type(4))) unsigned short us4;
typedef __attribute__((ext_vector_type(8))) short  s8;     // bf16x8 MFMA frag
typedef __attribute__((ext_vector_type(4))) float  f32x4;  // MFMA acc

__device__ __forceinline__ unsigned short f2bf(float f) {
  unsigned u = __float_as_uint(f);
  u += 0x7fffu + ((u >> 16) & 1u);
  return (unsigned short)(u >> 16);
}
__device__ __forceinline__ float elu1(float x) { return x > 0.f ? x + 1.f : __expf(x); }
__device__ __forceinline__ float gelu_erf(float x) { return 0.5f * x * (1.f + erff(x * 0.70710678118654752f)); }

__device__ __forceinline__ void async16(const void* g, void* l) {
  __builtin_amdgcn_global_load_lds((const __attribute__((address_space(1))) void*)g,
                                   (__attribute__((address_space(3))) void*)l, 16, 0, 0);
}

// RAW barrier: no compiler-attached waitcnt drain.
__device__ __forceinline__ void rawbar() {
  asm volatile("s_barrier" ::: "memory");
}

// LDS generic pointer -> 32-bit DS address
__device__ __forceinline__ unsigned l2u(const void* p) {
  return (unsigned)(size_t)(const __attribute__((address_space(3))) char*)p;
}
// asm ds_read_b128 with compile-time immediate offset
template<int OFF>
__device__ __forceinline__ void dsr(s8& d, unsigned base) {
  asm volatile("ds_read_b128 %0, %1 offset:%2" : "=v"(d) : "v"(base), "i"(OFF));
}

// ---------------- embedding: X = tok[idx] + pos, also bf16 copy ----------------
__global__ __launch_bounds__(256) void embed_kernel(
    const int* __restrict__ idx, const float* __restrict__ tok,
    const float* __restrict__ pos, float* __restrict__ X, unsigned short* __restrict__ XB)
{
  int g = blockIdx.x * 256 + threadIdx.x;
  int t = g >> 8;
  int c4 = (g & 255) * 4;
  int l = t & 2047;
  int tk = idx[t];
  f4 v = *(const f4*)(tok + (size_t)tk * 1024 + c4);
  f4 p = *(const f4*)(pos + (size_t)l * 1024 + c4);
  v += p;
  *(f4*)(X + (size_t)t * 1024 + c4) = v;
  us4 o = { f2bf(v[0]), f2bf(v[1]), f2bf(v[2]), f2bf(v[3]) };
  *(us4*)(XB + (size_t)t * 1024 + c4) = o;
}

// ---------------- f32 [K,N] -> bf16 [N,K] transpose-convert ----------------
__global__ __launch_bounds__(256) void transpose_cvt(
    const float* __restrict__ src, unsigned short* __restrict__ dst, int N, int K)
{
  __shared__ unsigned short t[64][72];
  int k0 = blockIdx.x * 64, n0 = blockIdx.y * 64;
  int tid = threadIdx.x;
#pragma unroll
  for (int i = 0; i < 4; ++i) {
    int f = tid + i * 256;
    int r = f >> 4, c4 = (f & 15) * 4;
    f4 v = *(const f4*)(src + (size_t)(k0 + r) * N + n0 + c4);
    us4 o = { f2bf(v[0]), f2bf(v[1]), f2bf(v[2]), f2bf(v[3]) };
    *(us4*)&t[r][c4] = o;
  }
  __syncthreads();
#pragma unroll
  for (int i = 0; i < 4; ++i) {
    int f = tid + i * 256;
    int nr = f >> 4, kc4 = (f & 15) * 4;
    us4 o = { t[kc4 + 0][nr], t[kc4 + 1][nr], t[kc4 + 2][nr], t[kc4 + 3][nr] };
    *(us4*)(dst + (size_t)(n0 + nr) * K + k0 + kc4) = o;
  }
}

// ---------------- old 128x128 bf16 MFMA GEMM (kept for QKV + fallback) --------
template<int EPI, int BF32>
__global__ __launch_bounds__(256) void gemm_bt(
    const unsigned short* __restrict__ A, const unsigned short* __restrict__ Bt,
    const float* __restrict__ Bf, const float* __restrict__ bias,
    void* __restrict__ Cv, int M, int N, int K, int mtiles)
{
  __shared__ unsigned short As[128 * 32];
  __shared__ unsigned short Bs[128 * 32];
  int bid = blockIdx.x;
  int mt = bid % mtiles, nt = bid / mtiles;
  int m0 = mt * 128, n0 = nt * 128;
  int tid = threadIdx.x, lane = tid & 63, w = tid >> 6;
  int wm = (w & 1) * 64, wn = (w >> 1) * 64;

  int c0 = w * 128 + lane, c1 = c0 + 64;
  size_t aO0 = (size_t)(m0 + (c0 >> 2)) * K + (size_t)((c0 & 3) * 8);
  size_t aO1 = (size_t)(m0 + (c1 >> 2)) * K + (size_t)((c1 & 3) * 8);
  size_t bO0 = (size_t)(n0 + (c0 >> 2)) * K + (size_t)((c0 & 3) * 8);
  size_t bO1 = (size_t)(n0 + (c1 >> 2)) * K + (size_t)((c1 & 3) * 8);
  unsigned short* lA0 = As + (w * 128) * 8;
  unsigned short* lA1 = As + (w * 128 + 64) * 8;
  unsigned short* lB0 = Bs + (w * 128) * 8;
  unsigned short* lB1 = Bs + (w * 128 + 64) * 8;

  f32x4 acc[4][4];
  f32x4 zz = {0.f, 0.f, 0.f, 0.f};
#pragma unroll
  for (int i = 0; i < 4; ++i)
#pragma unroll
    for (int j = 0; j < 4; ++j) acc[i][j] = zz;

  int rr = lane & 15, kh = (lane >> 4) * 8;
  const unsigned short* Ar = As + (wm + rr) * 32 + kh;
  const unsigned short* Br = Bs + (wn + rr) * 32 + kh;

  for (int k0 = 0; k0 < K; k0 += 32) {
    async16(A + aO0 + k0, lA0);
    async16(A + aO1 + k0, lA1);
    if constexpr (!BF32) {
      async16(Bt + bO0 + k0, lB0);
      async16(Bt + bO1 + k0, lB1);
    } else {
#pragma unroll
      for (int i = 0; i < 4; ++i) {
        int f = tid + i * 256;
        int kr = f >> 5, c4 = (f & 31) * 4;
        f4 v = *(const f4*)(Bf + (size_t)(k0 + kr) * N + n0 + c4);
#pragma unroll
        for (int e = 0; e < 4; ++e) Bs[(c4 + e) * 32 + kr] = f2bf(v[e]);
      }
    }
    __syncthreads();
    s8 af[4], bfr[4];
#pragma unroll
    for (int mi = 0; mi < 4; ++mi) af[mi] = *(const s8*)(Ar + mi * 512);
#pragma unroll
    for (int ni = 0; ni < 4; ++ni) bfr[ni] = *(const s8*)(Br + ni * 512);
#pragma unroll
    for (int mi = 0; mi < 4; ++mi)
#pragma unroll
      for (int ni = 0; ni < 4; ++ni)
        acc[mi][ni] = __builtin_amdgcn_mfma_f32_16x16x32_bf16(af[mi], bfr[ni], acc[mi][ni], 0, 0, 0);
    __syncthreads();
  }

  int cr = (lane >> 4) * 4;
#pragma unroll
  for (int mi = 0; mi < 4; ++mi) {
#pragma unroll
    for (int ni = 0; ni < 4; ++ni) {
      int gc = n0 + wn + ni * 16 + rr;
      float bv = (EPI > 0) ? bias[gc] : 0.f;
#pragma unroll
      for (int r = 0; r < 4; ++r) {
        int gr = m0 + wm + mi * 16 + cr + r;
        float v = acc[mi][ni][r] + bv;
        if constexpr (EPI == 1) {
          ((unsigned short*)Cv)[(size_t)gr * N + gc] = f2bf(gelu_erf(v));
        } else {
          ((float*)Cv)[(size_t)gr * N + gc] = v;
        }
      }
    }
  }
}

// ======== 256x256 bf16 GEMM, 1024 threads = 16 waves = 4 waves/SIMD ===========
// Same audited ring/ledger as r8's gemm128 (phase = 8 asm ds_read + 2 async16 +
// vmcnt(4) + rawbar + lgkmcnt(0) + 16 MFMA + rawbar), re-partitioned so the CU
// holds 4 waves/SIMD: per-wave output 64x64 (acc 64 VGPR, fits 128-VGPR cap of
// a 1024-thr block, no spill), wave grid 4Mx4N. 256-sq tile keeps panel FETCH
// at the r7 level (~1.6GB), unlike r8's 128-sq (4.4GB).
// Ledger (2 loads/wave/phase): region staged at phase q-3, certified by phase
// q-1's vmcnt(4) (leaves q-1's + q-2's 2+2 outstanding) + mid barrier; WAR:
// reads of a region complete at its phase's lgkmcnt(0), restage issued only
// after that phase's trailing barrier. Prologue: 6 loads, vmcnt(4) certifies
// pair #1; pairs #2,#3 certified by phases 1,2 (verified index-by-index).
template<int KB, typename STG>
__device__ __forceinline__ void phaseZ(
    unsigned AB, unsigned BB, f32x4 (&acc)[4][4], STG stg)
{
  s8 a0, a1, a2, a3, b0, b1, b2, b3;
  dsr<(0 * 2 + KB) * 1024>(a0, AB);
  dsr<(1 * 2 + KB) * 1024>(a1, AB);
  dsr<(2 * 2 + KB) * 1024>(a2, AB);
  dsr<(3 * 2 + KB) * 1024>(a3, AB);
  dsr<(0 * 2 + KB) * 1024>(b0, BB);
  dsr<(1 * 2 + KB) * 1024>(b1, BB);
  dsr<(2 * 2 + KB) * 1024>(b2, BB);
  dsr<(3 * 2 + KB) * 1024>(b3, BB);
  stg();
  asm volatile("s_waitcnt vmcnt(4)" ::: "memory");
  rawbar();
  asm volatile("s_waitcnt lgkmcnt(0)" ::: "memory");
  __builtin_amdgcn_sched_barrier(0);
  __builtin_amdgcn_s_setprio(1);
  acc[0][0] = __builtin_amdgcn_mfma_f32_16x16x32_bf16(a0, b0, acc[0][0], 0, 0, 0);
  acc[1][0] = __builtin_amdgcn_mfma_f32_16x16x32_bf16(a1, b0, acc[1][0], 0, 0, 0);
  acc[2][0] = __builtin_amdgcn_mfma_f32_16x16x32_bf16(a2, b0, acc[2][0], 0, 0, 0);
  acc[3][0] = __builtin_amdgcn_mfma_f32_16x16x32_bf16(a3, b0, acc[3][0], 0, 0, 0);
  acc[0][1] = __builtin_amdgcn_mfma_f32_16x16x32_bf16(a0, b1, acc[0][1], 0, 0, 0);
  acc[1][1] = __builtin_amdgcn_mfma_f32_16x16x32_bf16(a1, b1, acc[1][1], 0, 0, 0);
  acc[2][1] = __builtin_amdgcn_mfma_f32_16x16x32_bf16(a2, b1, acc[2][1], 0, 0, 0);
  acc[3][1] = __builtin_amdgcn_mfma_f32_16x16x32_bf16(a3, b1, acc[3][1], 0, 0, 0);
  acc[0][2] = __builtin_amdgcn_mfma_f32_16x16x32_bf16(a0, b2, acc[0][2], 0, 0, 0);
  acc[1][2] = __builtin_amdgcn_mfma_f32_16x16x32_bf16(a1, b2, acc[1][2], 0, 0, 0);
  acc[2][2] = __builtin_amdgcn_mfma_f32_16x16x32_bf16(a2, b2, acc[2][2], 0, 0, 0);
  acc[3][2] = __builtin_amdgcn_mfma_f32_16x16x32_bf16(a3, b2, acc[3][2], 0, 0, 0);
  acc[0][3] = __builtin_amdgcn_mfma_f32_16x16x32_bf16(a0, b3, acc[0][3], 0, 0, 0);
  acc[1][3] = __builtin_amdgcn_mfma_f32_16x16x32_bf16(a1, b3, acc[1][3], 0, 0, 0);
  acc[2][3] = __builtin_amdgcn_mfma_f32_16x16x32_bf16(a2, b3, acc[2][3], 0, 0, 0);
  acc[3][3] = __builtin_amdgcn_mfma_f32_16x16x32_bf16(a3, b3, acc[3][3], 0, 0, 0);
  __builtin_amdgcn_s_setprio(0);
  __builtin_amdgcn_sched_barrier(0);
  rawbar();
}

template<int EPI>  // 1 = bias+GELU->bf16, 2 = bias->f32
__global__ __launch_bounds__(1024) void gemm1k(
    const unsigned short* __restrict__ A, const unsigned short* __restrict__ Bt,
    const float* __restrict__ bias, void* __restrict__ Cv,
    int M, int N, int K, int mtiles)
{
  __shared__ __align__(16) char A0r[32768];
  __shared__ __align__(16) char B0r[32768];
  __shared__ __align__(16) char A1r[32768];
  __shared__ __align__(16) char B1r[32768];

  const int tid = threadIdx.x, lane = tid & 63, w = tid >> 6;  // w in 0..15
  const int wm = w >> 2, wn = w & 3;
  const int NT = K >> 6;

  // bijective XCD swizzle (m204)
  int nwg = gridDim.x, orig = blockIdx.x;
  int q = nwg >> 3, r = nwg & 7;
  int xcd = orig & 7, lin = orig >> 3;
  int swz = (xcd < r ? xcd * (q + 1) : r * (q + 1) + (xcd - r) * q) + lin;
  int mt = swz % mtiles, nt = swz / mtiles;
  int m0 = mt * 256, n0 = nt * 256;

  // staging: wave w owns 1KB block w of each region. LDS block (w, kb) holds
  // rows w*16+(lane&15), k-chunk kb*32+(lane>>4)*8 of the tile. One async16
  // per wave per stg call; per-lane global source, wave-uniform LDS dest.
  const unsigned short* aP = A + (size_t)(m0 + w * 16 + (lane & 15)) * K + ((lane >> 4) << 3);
  const unsigned short* bP = Bt + (size_t)(n0 + w * 16 + (lane & 15)) * K + ((lane >> 4) << 3);

  auto stgA = [&](char* reg, int kt, int kb) {
    int ktc = kt < NT ? kt : NT - 1;
    async16(aP + ktc * 64 + kb * 32, reg + w * 2048 + kb * 1024);
  };
  auto stgB = [&](char* reg, int kt, int kb) {
    int ktc = kt < NT ? kt : NT - 1;
    async16(bP + ktc * 64 + kb * 32, reg + w * 2048 + kb * 1024);
  };

  // fragment read bases: wave (wm,wn) consumes A blocks wm*4..+3, B wn*4..+3
  const unsigned AB0 = l2u(A0r + wm * 8192 + lane * 16);
  const unsigned BB0 = l2u(B0r + wn * 8192 + lane * 16);
  const unsigned AB1 = l2u(A1r + wm * 8192 + lane * 16);
  const unsigned BB1 = l2u(B1r + wn * 8192 + lane * 16);

  f32x4 acc[4][4];
  f32x4 zz = {0.f, 0.f, 0.f, 0.f};
#pragma unroll
  for (int i = 0; i < 4; ++i)
#pragma unroll
    for (int j = 0; j < 4; ++j) acc[i][j] = zz;

  // prologue: tile0 full + tile1 kb0 (6 loads/wave); vmcnt(4) certifies pair#1
  stgA(A0r, 0, 0); stgB(B0r, 0, 0);
  stgA(A0r, 0, 1); stgB(B0r, 0, 1);
  stgA(A1r, 1, 0); stgB(B1r, 1, 0);
  asm volatile("s_waitcnt vmcnt(4)" ::: "memory");
  rawbar();

  for (int te = 0; te < NT; te += 2) {
    // tile te (buf0)
    phaseZ<0>(AB0, BB0, acc, [&] { stgA(A1r, te + 1, 1); stgB(B1r, te + 1, 1); });
    phaseZ<1>(AB0, BB0, acc, [&] { stgA(A0r, te + 2, 0); stgB(B0r, te + 2, 0); });
    // tile te+1 (buf1)
    phaseZ<0>(AB1, BB1, acc, [&] { stgA(A0r, te + 2, 1); stgB(B0r, te + 2, 1); });
    phaseZ<1>(AB1, BB1, acc, [&] { stgA(A1r, te + 3, 0); stgB(B1r, te + 3, 0); });
  }

  asm volatile("s_waitcnt vmcnt(0) lgkmcnt(0)" ::: "memory");
  __builtin_amdgcn_sched_barrier(0);

  // epilogue: C/D map col=lane&15, row=(lane>>4)*4+reg
  int rr = lane & 15, cr = (lane >> 4) * 4;
#pragma unroll
  for (int mi = 0; mi < 4; ++mi) {
#pragma unroll
    for (int ni = 0; ni < 4; ++ni) {
      int gc = n0 + wn * 64 + ni * 16 + rr;
      float bv = bias[gc];
#pragma unroll
      for (int rg = 0; rg < 4; ++rg) {
        int gr = m0 + wm * 64 + mi * 16 + cr + rg;
        float v = acc[mi][ni][rg] + bv;
        if constexpr (EPI == 1) {
          ((unsigned short*)Cv)[(size_t)gr * N + gc] = f2bf(gelu_erf(v));
        } else {
          ((float*)Cv)[(size_t)gr * N + gc] = v;
        }
      }
    }
  }
}

// ---------------- per-chunk K^T V and K sums ----------------
__global__ __launch_bounds__(256) void chunk_sums(
    const float* __restrict__ QKV, float* __restrict__ KVc, float* __restrict__ Ksum)
{
  __shared__ float Ks[64][68], Vs[64][68];
  int blk = blockIdx.x, t0 = blk * 64, tid = threadIdx.x;
#pragma unroll
  for (int i = 0; i < 4; ++i) {
    int f = tid + i * 256;
    int r = f >> 4, c4 = (f & 15) * 4;
    const float* s = QKV + (size_t)(t0 + r) * 256;
    f4 k = *(const f4*)(s + 64 + c4);
    f4 v = *(const f4*)(s + 128 + c4);
#pragma unroll
    for (int e = 0; e < 4; ++e) { Ks[r][c4 + e] = elu1(k[e]); Vs[r][c4 + e] = v[e]; }
  }
  __syncthreads();
  int i0 = tid >> 2, jb = (tid & 3) * 16;
  f4 a0 = {0,0,0,0}, a1 = {0,0,0,0}, a2 = {0,0,0,0}, a3 = {0,0,0,0};
  for (int t = 0; t < 64; ++t) {
    float kk = Ks[t][i0];
    a0 += kk * (*(const f4*)&Vs[t][jb]);
    a1 += kk * (*(const f4*)&Vs[t][jb + 4]);
    a2 += kk * (*(const f4*)&Vs[t][jb + 8]);
    a3 += kk * (*(const f4*)&Vs[t][jb + 12]);
  }
  float* d = KVc + (size_t)blk * 4096 + i0 * 64 + jb;
  *(f4*)(d) = a0; *(f4*)(d + 4) = a1; *(f4*)(d + 8) = a2; *(f4*)(d + 12) = a3;
  if (tid < 64) {
    float s = 0.f;
    for (int t = 0; t < 64; ++t) s += Ks[t][tid];
    Ksum[(size_t)blk * 64 + tid] = s;
  }
}

// ---------------- exclusive prefix of chunk states ----------------
__global__ __launch_bounds__(256) void prefix_state(
    const float* __restrict__ KVc, const float* __restrict__ Ksum,
    float* __restrict__ KVp, float* __restrict__ Ksump)
{
  int b = blockIdx.x >> 3, seg = blockIdx.x & 7;
  int e = seg * 512 + threadIdx.x * 2;
  f2 run = {0.f, 0.f};
#pragma unroll
  for (int c = 0; c < 32; ++c) {
    size_t base = ((size_t)b * 32 + c) * 4096 + e;
    *(f2*)(KVp + base) = run;
    run += *(const f2*)(KVc + base);
  }
  if (seg == 0 && threadIdx.x < 64) {
    float rs = 0.f; int i = threadIdx.x;
#pragma unroll
    for (int c = 0; c < 32; ++c) {
      size_t base = ((size_t)b * 32 + c) * 64 + i;
      Ksump[base] = rs;
      rs += Ksum[base];
    }
  }
}

// ---------------- per-chunk normalized attention coefficients ----------------
__global__ __launch_bounds__(256) void attn_ns(
    const float* __restrict__ QKV, const float* __restrict__ KVp,
    const float* __restrict__ Ksump, float* __restrict__ NsG)
{
  __shared__ float Qs[64][68], Ks[64][68], Vs[64][68], Ss[64][68], Ps[64][68];
  __shared__ float ksps[64];
  int blk = blockIdx.x, t0 = blk * 64, tid = threadIdx.x;
#pragma unroll
  for (int i = 0; i < 4; ++i) {
    int f = tid + i * 256;
    int r = f >> 4, c4 = (f & 15) * 4;
    const float* s = QKV + (size_t)(t0 + r) * 256;
    f4 q = *(const f4*)(s + c4);
    f4 k = *(const f4*)(s + 64 + c4);
    f4 v = *(const f4*)(s + 128 + c4);
    f4 p = *(const f4*)(KVp + (size_t)blk * 4096 + r * 64 + c4);
#pragma unroll
    for (int e = 0; e < 4; ++e) {
      Qs[r][c4 + e] = elu1(q[e]); Ks[r][c4 + e] = elu1(k[e]);
      Vs[r][c4 + e] = v[e];       Ps[r][c4 + e] = p[e];
    }
  }
  if (tid < 64) ksps[tid] = Ksump[(size_t)blk * 64 + tid];
  __syncthreads();
  int tq = tid >> 2, jb = (tid & 3) * 16;
#pragma unroll
  for (int jj = 0; jj < 16; ++jj) {
    int tk = jb + jj;
    float s = 0.f;
    if (tk <= tq) {
#pragma unroll
      for (int k4 = 0; k4 < 16; ++k4) {
        f4 q = *(const f4*)&Qs[tq][k4 * 4];
        f4 k = *(const f4*)&Ks[tk][k4 * 4];
        s += q[0] * k[0] + q[1] * k[1] + q[2] * k[2] + q[3] * k[3];
      }
    }
    Ss[tq][tk] = s;
  }
  __syncthreads();
  f4 a0 = {0,0,0,0}, a1 = {0,0,0,0}, a2 = {0,0,0,0}, a3 = {0,0,0,0};
  for (int t = 0; t < 64; ++t) {
    float s = Ss[tq][t];
    a0 += s * (*(const f4*)&Vs[t][jb]);
    a1 += s * (*(const f4*)&Vs[t][jb + 4]);
    a2 += s * (*(const f4*)&Vs[t][jb + 8]);
    a3 += s * (*(const f4*)&Vs[t][jb + 12]);
  }
  for (int k = 0; k < 64; ++k) {
    float q = Qs[tq][k];
    a0 += q * (*(const f4*)&Ps[k][jb]);
    a1 += q * (*(const f4*)&Ps[k][jb + 4]);
    a2 += q * (*(const f4*)&Ps[k][jb + 8]);
    a3 += q * (*(const f4*)&Ps[k][jb + 12]);
  }
  float den = 0.f;
  for (int t = 0; t < 64; ++t) den += Ss[tq][t];
  for (int k = 0; k < 64; ++k) den += Qs[tq][k] * ksps[k];
  float inv = 1.f / (den + 1e-6f);
  float* d = NsG + (size_t)(t0 + tq) * 64 + jb;
  *(f4*)(d)      = a0 * inv;
  *(f4*)(d + 4)  = a1 * inv;
  *(f4*)(d + 8)  = a2 * inv;
  *(f4*)(d + 12) = a3 * inv;
}

// ---------------- attn @ Wo + residual into X ----------------
__global__ __launch_bounds__(256) void attn_apply(
    const float* __restrict__ NsG, const float* __restrict__ Wo, float* __restrict__ X)
{
  __shared__ float Ns[64][68];
  __shared__ float Wt[64][260];
  int chunk = blockIdx.x >> 2, dg = blockIdx.x & 3;
  int t0 = chunk * 64, d0 = dg * 256, tid = threadIdx.x;
#pragma unroll
  for (int i = 0; i < 4; ++i) {
    int f = tid + i * 256;
    int r = f >> 4, c4 = (f & 15) * 4;
    *(f4*)&Ns[r][c4] = *(const f4*)(NsG + (size_t)(t0 + r) * 64 + c4);
  }
#pragma unroll
  for (int i = 0; i < 16; ++i) {
    int f = tid + i * 256;
    int r = f >> 6, c4 = (f & 63) * 4;
    *(f4*)&Wt[r][c4] = *(const f4*)(Wo + (size_t)r * 1024 + d0 + c4);
  }
  __syncthreads();
  int w = tid >> 6, lane = tid & 63;
  for (int ts = 0; ts < 16; ++ts) {
    int t = w * 16 + ts;
    float a0 = 0.f, a1 = 0.f, a2 = 0.f, a3 = 0.f;
#pragma unroll
    for (int j = 0; j < 64; ++j) {
      float nv = Ns[t][j];
      a0 += nv * Wt[j][lane];
      a1 += nv * Wt[j][64 + lane];
      a2 += nv * Wt[j][128 + lane];
      a3 += nv * Wt[j][192 + lane];
    }
    size_t o = (size_t)(t0 + t) * 1024 + d0 + lane;
    X[o]       += a0;
    X[o + 64]  += a1;
    X[o + 128] += a2;
    X[o + 192] += a3;
  }
}

// ---------------- layernorm over D=1024, writes f32 + bf16 ----------------
__global__ __launch_bounds__(256) void layernorm_kernel(
    float* __restrict__ X, unsigned short* __restrict__ XB,
    const float* __restrict__ g, const float* __restrict__ b)
{
  int t = blockIdx.x * 4 + (threadIdx.x >> 6);
  int lane = threadIdx.x & 63;
  float* row = X + (size_t)t * 1024;
  f4 v[4];
  float s = 0.f, s2 = 0.f;
#pragma unroll
  for (int i = 0; i < 4; ++i) {
    v[i] = *(const f4*)(row + (i * 64 + lane) * 4);
#pragma unroll
    for (int e = 0; e < 4; ++e) { s += v[i][e]; s2 += v[i][e] * v[i][e]; }
  }
#pragma unroll
  for (int off = 32; off > 0; off >>= 1) {
    s  += __shfl_xor(s, off, 64);
    s2 += __shfl_xor(s2, off, 64);
  }
  float mean = s * (1.f / 1024.f);
  float var = s2 * (1.f / 1024.f) - mean * mean;
  float rstd = rsqrtf(var + 1e-5f);
#pragma unroll
  for (int i = 0; i < 4; ++i) {
    int d = (i * 64 + lane) * 4;
    f4 gv = *(const f4*)(g + d);
    f4 bv = *(const f4*)(b + d);
    f4 y;
#pragma unroll
    for (int e = 0; e < 4; ++e) y[e] = (v[i][e] - mean) * rstd * gv[e] + bv[e];
    *(f4*)(row + d) = y;
    us4 o = { f2bf(y[0]), f2bf(y[1]), f2bf(y[2]), f2bf(y[3]) };
    *(us4*)(XB + (size_t)t * 1024 + d) = o;
  }
}

extern "C" void kernel_launch(void* const* d_in, const int* in_sizes, int n_in,
                              void* d_out, int out_size, void* d_ws, size_t ws_size,
                              hipStream_t stream) {
  (void)in_sizes; (void)n_in; (void)out_size;
  const int*   idx = (const int*)d_in[0];
  const float* tok = (const float*)d_in[1];
  const float* pos = (const float*)d_in[2];
  const float* Wq  = (const float*)d_in[3];
  const float* Wk  = (const float*)d_in[4];
  const float* Wv  = (const float*)d_in[5];
  const float* Wo  = (const float*)d_in[6];
  const float* ng  = (const float*)d_in[7];
  const float* nb  = (const float*)d_in[8];
  const float* ong = (const float*)d_in[9];
  const float* onb = (const float*)d_in[10];
  const float* W1  = (const float*)d_in[11];
  const float* b1  = (const float*)d_in[12];
  const float* W2  = (const float*)d_in[13];
  const float* b2  = (const float*)d_in[14];
  float* out = (float*)d_out;
  char* ws = (char*)d_ws;

  float* X            = (float*)(ws + 0);
  unsigned short* XB  = (unsigned short*)(ws + 16777216);
  unsigned short* QT0 = (unsigned short*)(ws + 25165824);
  unsigned short* QT1 = (unsigned short*)(ws + 25690112);
  float* QKVB         = (float*)(ws + 26214400);
  float* KVC          = (float*)(ws + 30408704);
  float* KSUM         = (float*)(ws + 31457280);
  float* KVP          = (float*)(ws + 31490048);
  float* KSP          = (float*)(ws + 32538624);
  unsigned short* W1T = (unsigned short*)(ws + 32571392);
  unsigned short* H   = (unsigned short*)(ws + 40960000);
  unsigned short* W2T = (unsigned short*)(ws + 74514432);
  float* NSG = KVC;  // reuse: KVC dead after prefix_state
  bool bigws = ws_size >= 336658432ull;

  hipMemsetAsync(QT0, 0, 524288, stream);
  hipMemsetAsync(QT1, 0, 524288, stream);
  transpose_cvt<<<dim3(16, 1), 256, 0, stream>>>(Wq,          QT0,              64, 1024);
  transpose_cvt<<<dim3(16, 1), 256, 0, stream>>>(Wk,          QT0 + 64 * 1024,  64, 1024);
  transpose_cvt<<<dim3(16, 1), 256, 0, stream>>>(Wv,          QT0 + 128 * 1024, 64, 1024);
  transpose_cvt<<<dim3(16, 1), 256, 0, stream>>>(Wq + 65536,  QT1,              64, 1024);
  transpose_cvt<<<dim3(16, 1), 256, 0, stream>>>(Wk + 65536,  QT1 + 64 * 1024,  64, 1024);
  transpose_cvt<<<dim3(16, 1), 256, 0, stream>>>(Wv + 65536,  QT1 + 128 * 1024, 64, 1024);
  transpose_cvt<<<dim3(16, 64), 256, 0, stream>>>(W1, W1T, 4096, 1024);
  if (bigws)
    transpose_cvt<<<dim3(64, 500), 256, 0, stream>>>(W2, W2T, 32000, 4096);

  embed_kernel<<<4096, 256, 0, stream>>>(idx, tok, pos, X, XB);

  for (int layer = 0; layer < 2; ++layer) {
    const unsigned short* QT = layer ? QT1 : QT0;
    gemm_bt<0, 0><<<64, 256, 0, stream>>>(XB, QT, nullptr, nullptr, QKVB, 4096, 256, 1024, 32);
    chunk_sums<<<64, 256, 0, stream>>>(QKVB, KVC, KSUM);
    prefix_state<<<16, 256, 0, stream>>>(KVC, KSUM, KVP, KSP);
    attn_ns<<<64, 256, 0, stream>>>(QKVB, KVP, KSP, NSG);
    attn_apply<<<256, 256, 0, stream>>>(NSG, Wo + (size_t)layer * 65536, X);
    layernorm_kernel<<<1024, 256, 0, stream>>>(X, XB, ng + layer * 1024, nb + layer * 1024);
  }
  layernorm_kernel<<<1024, 256, 0, stream>>>(X, XB, ong, onb);

  gemm1k<1><<<256, 1024, 0, stream>>>(XB, W1T, b1, H, 4096, 4096, 1024, 16);
  if (bigws)
    gemm1k<2><<<2000, 1024, 0, stream>>>(H, W2T, b2, out, 4096, 32000, 4096, 16);
  else
    gemm_bt<2, 1><<<8000, 256, 0, stream>>>(H, nullptr, W2, b2, out, 4096, 32000, 4096, 32);
}

// Round 10
// 1598.537 us; speedup vs baseline: 1.5836x; 1.0647x over previous
//
#include <hip/hip_runtime.h>

typedef __attribute__((ext_vector_type(4))) float  f4;
typedef __attribute__((ext_vector_type(2))) float  f2;
typedef __attribute__((ext_vector_type(4))) unsigned short us4;
typedef __attribute__((ext_vector_type(8))) short  s8;     // bf16x8 MFMA frag
typedef __attribute__((ext_vector_type(4))) float  f32x4;  // MFMA acc

__device__ __forceinline__ unsigned short f2bf(float f) {
  unsigned u = __float_as_uint(f);
  u += 0x7fffu + ((u >> 16) & 1u);
  return (unsigned short)(u >> 16);
}
__device__ __forceinline__ float elu1(float x) { return x > 0.f ? x + 1.f : __expf(x); }
__device__ __forceinline__ float gelu_erf(float x) { return 0.5f * x * (1.f + erff(x * 0.70710678118654752f)); }

__device__ __forceinline__ void async16(const void* g, void* l) {
  __builtin_amdgcn_global_load_lds((const __attribute__((address_space(1))) void*)g,
                                   (__attribute__((address_space(3))) void*)l, 16, 0, 0);
}

// RAW barrier: no compiler-attached waitcnt drain.
__device__ __forceinline__ void rawbar() {
  asm volatile("s_barrier" ::: "memory");
}

// LDS generic pointer -> 32-bit DS address
__device__ __forceinline__ unsigned l2u(const void* p) {
  return (unsigned)(size_t)(const __attribute__((address_space(3))) char*)p;
}
// asm ds_read_b128 with compile-time immediate offset
template<int OFF>
__device__ __forceinline__ void dsr(s8& d, unsigned base) {
  asm volatile("ds_read_b128 %0, %1 offset:%2" : "=v"(d) : "v"(base), "i"(OFF));
}

// ---------------- embedding: X = tok[idx] + pos, also bf16 copy ----------------
__global__ __launch_bounds__(256) void embed_kernel(
    const int* __restrict__ idx, const float* __restrict__ tok,
    const float* __restrict__ pos, float* __restrict__ X, unsigned short* __restrict__ XB)
{
  int g = blockIdx.x * 256 + threadIdx.x;
  int t = g >> 8;
  int c4 = (g & 255) * 4;
  int l = t & 2047;
  int tk = idx[t];
  f4 v = *(const f4*)(tok + (size_t)tk * 1024 + c4);
  f4 p = *(const f4*)(pos + (size_t)l * 1024 + c4);
  v += p;
  *(f4*)(X + (size_t)t * 1024 + c4) = v;
  us4 o = { f2bf(v[0]), f2bf(v[1]), f2bf(v[2]), f2bf(v[3]) };
  *(us4*)(XB + (size_t)t * 1024 + c4) = o;
}

// ---------------- f32 [K,N] -> bf16 [N,K] transpose-convert ----------------
__global__ __launch_bounds__(256) void transpose_cvt(
    const float* __restrict__ src, unsigned short* __restrict__ dst, int N, int K)
{
  __shared__ unsigned short t[64][72];
  int k0 = blockIdx.x * 64, n0 = blockIdx.y * 64;
  int tid = threadIdx.x;
#pragma unroll
  for (int i = 0; i < 4; ++i) {
    int f = tid + i * 256;
    int r = f >> 4, c4 = (f & 15) * 4;
    f4 v = *(const f4*)(src + (size_t)(k0 + r) * N + n0 + c4);
    us4 o = { f2bf(v[0]), f2bf(v[1]), f2bf(v[2]), f2bf(v[3]) };
    *(us4*)&t[r][c4] = o;
  }
  __syncthreads();
#pragma unroll
  for (int i = 0; i < 4; ++i) {
    int f = tid + i * 256;
    int nr = f >> 4, kc4 = (f & 15) * 4;
    us4 o = { t[kc4 + 0][nr], t[kc4 + 1][nr], t[kc4 + 2][nr], t[kc4 + 3][nr] };
    *(us4*)(dst + (size_t)(n0 + nr) * K + k0 + kc4) = o;
  }
}

// ---------------- 128x128 bf16 MFMA GEMM (QKV, W1, fallback) ----------------
template<int EPI, int BF32>
__global__ __launch_bounds__(256) void gemm_bt(
    const unsigned short* __restrict__ A, const unsigned short* __restrict__ Bt,
    const float* __restrict__ Bf, const float* __restrict__ bias,
    void* __restrict__ Cv, int M, int N, int K, int mtiles)
{
  __shared__ unsigned short As[128 * 32];
  __shared__ unsigned short Bs[128 * 32];
  int bid = blockIdx.x;
  int mt = bid % mtiles, nt = bid / mtiles;
  int m0 = mt * 128, n0 = nt * 128;
  int tid = threadIdx.x, lane = tid & 63, w = tid >> 6;
  int wm = (w & 1) * 64, wn = (w >> 1) * 64;

  int c0 = w * 128 + lane, c1 = c0 + 64;
  size_t aO0 = (size_t)(m0 + (c0 >> 2)) * K + (size_t)((c0 & 3) * 8);
  size_t aO1 = (size_t)(m0 + (c1 >> 2)) * K + (size_t)((c1 & 3) * 8);
  size_t bO0 = (size_t)(n0 + (c0 >> 2)) * K + (size_t)((c0 & 3) * 8);
  size_t bO1 = (size_t)(n0 + (c1 >> 2)) * K + (size_t)((c1 & 3) * 8);
  unsigned short* lA0 = As + (w * 128) * 8;
  unsigned short* lA1 = As + (w * 128 + 64) * 8;
  unsigned short* lB0 = Bs + (w * 128) * 8;
  unsigned short* lB1 = Bs + (w * 128 + 64) * 8;

  f32x4 acc[4][4];
  f32x4 zz = {0.f, 0.f, 0.f, 0.f};
#pragma unroll
  for (int i = 0; i < 4; ++i)
#pragma unroll
    for (int j = 0; j < 4; ++j) acc[i][j] = zz;

  int rr = lane & 15, kh = (lane >> 4) * 8;
  const unsigned short* Ar = As + (wm + rr) * 32 + kh;
  const unsigned short* Br = Bs + (wn + rr) * 32 + kh;

  for (int k0 = 0; k0 < K; k0 += 32) {
    async16(A + aO0 + k0, lA0);
    async16(A + aO1 + k0, lA1);
    if constexpr (!BF32) {
      async16(Bt + bO0 + k0, lB0);
      async16(Bt + bO1 + k0, lB1);
    } else {
#pragma unroll
      for (int i = 0; i < 4; ++i) {
        int f = tid + i * 256;
        int kr = f >> 5, c4 = (f & 31) * 4;
        f4 v = *(const f4*)(Bf + (size_t)(k0 + kr) * N + n0 + c4);
#pragma unroll
        for (int e = 0; e < 4; ++e) Bs[(c4 + e) * 32 + kr] = f2bf(v[e]);
      }
    }
    __syncthreads();
    s8 af[4], bfr[4];
#pragma unroll
    for (int mi = 0; mi < 4; ++mi) af[mi] = *(const s8*)(Ar + mi * 512);
#pragma unroll
    for (int ni = 0; ni < 4; ++ni) bfr[ni] = *(const s8*)(Br + ni * 512);
#pragma unroll
    for (int mi = 0; mi < 4; ++mi)
#pragma unroll
      for (int ni = 0; ni < 4; ++ni)
        acc[mi][ni] = __builtin_amdgcn_mfma_f32_16x16x32_bf16(af[mi], bfr[ni], acc[mi][ni], 0, 0, 0);
    __syncthreads();
  }

  int cr = (lane >> 4) * 4;
#pragma unroll
  for (int mi = 0; mi < 4; ++mi) {
#pragma unroll
    for (int ni = 0; ni < 4; ++ni) {
      int gc = n0 + wn + ni * 16 + rr;
      float bv = (EPI > 0) ? bias[gc] : 0.f;
#pragma unroll
      for (int r = 0; r < 4; ++r) {
        int gr = m0 + wm + mi * 16 + cr + r;
        float v = acc[mi][ni][r] + bv;
        if constexpr (EPI == 1) {
          ((unsigned short*)Cv)[(size_t)gr * N + gc] = f2bf(gelu_erf(v));
        } else {
          ((float*)Cv)[(size_t)gr * N + gc] = v;
        }
      }
    }
  }
}

// ====== 256x256 bf16 GEMM v2: per-TILE barrier epoch, batched lgkm walls =====
// 512 thr = 8 waves (2M x 4N); BK=64; LDS 128KB; fragment-contiguous layout
// (r5's, 0 bank conflicts, correctness-proven). Per K-tile (ONE barrier):
//   issue all 24 asm ds_read_b128 (B 8, A 16)
//   lgkmcnt(12) -> 16 MFMA (f0,f1)    // reads f2..f7 still in flight
//   lgkmcnt(8)  -> 16 MFMA (f2,f3)    // LDS pipe drains UNDER the MFMA stream
//   lgkmcnt(4)  -> 16 MFMA (f4,f5)
//   lgkmcnt(0)  -> 16 MFMA (f6,f7)
//   stage tile t+2 into this buffer (8 async16) ; vmcnt(8) ; s_barrier
// This removes the CU-wide {LDS burst | MFMA burst} alternation that pinned
// r2-r9 at 37% MfmaUtil (r9: doubling occupancy changed nothing -> shared-
// resource serialization, not latency). Ledger: RAW: tile t's vmcnt(8)
// certifies t+1's 8 stages before the barrier that opens t+1's reads (prologue
// stages t0,t1=16 loads; vmcnt(8) certifies t0). WAR: stage of buf d issues
// after the wave's lgkmcnt(0) (all own reads served); cross-wave, all reads
// enter the DS queue within ~100cyc of barrier release and are served before
// any wave finishes its 64-MFMA body + >=200cyc vmem landing latency.
template<int EPI>  // 1 = bias+GELU->bf16, 2 = bias->f32
__global__ __launch_bounds__(512) void gemm2(
    const unsigned short* __restrict__ A, const unsigned short* __restrict__ Bt,
    const float* __restrict__ bias, void* __restrict__ Cv,
    int M, int N, int K, int mtiles)
{
  __shared__ __align__(16) char A0r[32768];
  __shared__ __align__(16) char B0r[32768];
  __shared__ __align__(16) char A1r[32768];
  __shared__ __align__(16) char B1r[32768];

  const int tid = threadIdx.x, lane = tid & 63, w = tid >> 6;
  const int wm = w >> 2, wn = w & 3;
  const int NT = K >> 6;

  // bijective XCD swizzle (m204)
  int nwg = gridDim.x, orig = blockIdx.x;
  int q = nwg >> 3, r = nwg & 7;
  int xcd = orig & 7, lin = orig >> 3;
  int swz = (xcd < r ? xcd * (q + 1) : r * (q + 1) + (xcd - r) * q) + lin;
  int mt = swz % mtiles, nt = swz / mtiles;
  int m0 = mt * 256, n0 = nt * 256;

  // staging (r5-proven): per-lane global source, wave-uniform LDS dest
  const size_t klane8 = (size_t)((lane >> 4) << 3);
  const size_t arow0 = (size_t)(m0 + w * 32 + (lane & 15)) * K;
  const size_t arow1 = arow0 + (size_t)16 * K;
  const size_t brow0 = (size_t)(n0 + w * 32 + (lane & 15)) * K;
  const size_t brow1 = brow0 + (size_t)16 * K;

  auto stgA = [&](char* reg, int kt, int kb) {
    int ktc = kt < NT ? kt : NT - 1;
    size_t kk = (size_t)ktc * 64 + (size_t)(kb * 32) + klane8;
    char* d = reg + w * 4096 + kb * 1024;
    async16(A + arow0 + kk, d);
    async16(A + arow1 + kk, d + 2048);
  };
  auto stgB = [&](char* reg, int kt, int kb) {
    int ktc = kt < NT ? kt : NT - 1;
    size_t kk = (size_t)ktc * 64 + (size_t)(kb * 32) + klane8;
    char* d = reg + w * 4096 + kb * 1024;
    async16(Bt + brow0 + kk, d);
    async16(Bt + brow1 + kk, d + 2048);
  };

  // fragment read bases (32-bit DS addresses)
  const unsigned AB0 = l2u(A0r + wm * 16384 + lane * 16);
  const unsigned BB0 = l2u(B0r + wn * 8192 + lane * 16);
  const unsigned AB1 = l2u(A1r + wm * 16384 + lane * 16);
  const unsigned BB1 = l2u(B1r + wn * 8192 + lane * 16);

  f32x4 acc[8][4];
  f32x4 zz = {0.f, 0.f, 0.f, 0.f};
#pragma unroll
  for (int i = 0; i < 8; ++i)
#pragma unroll
    for (int j = 0; j < 4; ++j) acc[i][j] = zz;

  // prologue: tile0 -> buf0, tile1 -> buf1 (16 loads); vmcnt(8) certifies t0
  stgA(A0r, 0, 0); stgA(A0r, 0, 1); stgB(B0r, 0, 0); stgB(B0r, 0, 1);
  stgA(A1r, 1, 0); stgA(A1r, 1, 1); stgB(B1r, 1, 0); stgB(B1r, 1, 1);
  asm volatile("s_waitcnt vmcnt(8)" ::: "memory");
  rawbar();

  for (int t = 0; t < NT; ++t) {
    const int odd = t & 1;
    const unsigned AB = odd ? AB1 : AB0;
    const unsigned BB = odd ? BB1 : BB0;
    char* Ad = odd ? A1r : A0r;
    char* Bd = odd ? B1r : B0r;

    s8 bf[8], af[16];
    // issue all B reads (8): bf[ni*2+kb]
    dsr<(0 * 2 + 0) * 1024>(bf[0], BB);
    dsr<(0 * 2 + 1) * 1024>(bf[1], BB);
    dsr<(1 * 2 + 0) * 1024>(bf[2], BB);
    dsr<(1 * 2 + 1) * 1024>(bf[3], BB);
    dsr<(2 * 2 + 0) * 1024>(bf[4], BB);
    dsr<(2 * 2 + 1) * 1024>(bf[5], BB);
    dsr<(3 * 2 + 0) * 1024>(bf[6], BB);
    dsr<(3 * 2 + 1) * 1024>(bf[7], BB);
    // issue all A reads (16): af[f*2+kb]
    dsr<(0 * 2 + 0) * 1024>(af[0], AB);
    dsr<(0 * 2 + 1) * 1024>(af[1], AB);
    dsr<(1 * 2 + 0) * 1024>(af[2], AB);
    dsr<(1 * 2 + 1) * 1024>(af[3], AB);
    dsr<(2 * 2 + 0) * 1024>(af[4], AB);
    dsr<(2 * 2 + 1) * 1024>(af[5], AB);
    dsr<(3 * 2 + 0) * 1024>(af[6], AB);
    dsr<(3 * 2 + 1) * 1024>(af[7], AB);
    dsr<(4 * 2 + 0) * 1024>(af[8], AB);
    dsr<(4 * 2 + 1) * 1024>(af[9], AB);
    dsr<(5 * 2 + 0) * 1024>(af[10], AB);
    dsr<(5 * 2 + 1) * 1024>(af[11], AB);
    dsr<(6 * 2 + 0) * 1024>(af[12], AB);
    dsr<(6 * 2 + 1) * 1024>(af[13], AB);
    dsr<(7 * 2 + 0) * 1024>(af[14], AB);
    dsr<(7 * 2 + 1) * 1024>(af[15], AB);

    // wall 1: B(8) + A f0,f1 ready; 12 reads still in flight under the MFMAs
    asm volatile("s_waitcnt lgkmcnt(12)" ::: "memory");
    __builtin_amdgcn_sched_barrier(0);
    __builtin_amdgcn_s_setprio(1);
#pragma unroll
    for (int ni = 0; ni < 4; ++ni) {
#pragma unroll
      for (int f = 0; f < 2; ++f) {
        acc[f][ni] = __builtin_amdgcn_mfma_f32_16x16x32_bf16(af[f * 2 + 0], bf[ni * 2 + 0], acc[f][ni], 0, 0, 0);
        acc[f][ni] = __builtin_amdgcn_mfma_f32_16x16x32_bf16(af[f * 2 + 1], bf[ni * 2 + 1], acc[f][ni], 0, 0, 0);
      }
    }
    __builtin_amdgcn_s_setprio(0);
    asm volatile("s_waitcnt lgkmcnt(8)" ::: "memory");
    __builtin_amdgcn_sched_barrier(0);
    __builtin_amdgcn_s_setprio(1);
#pragma unroll
    for (int ni = 0; ni < 4; ++ni) {
#pragma unroll
      for (int f = 2; f < 4; ++f) {
        acc[f][ni] = __builtin_amdgcn_mfma_f32_16x16x32_bf16(af[f * 2 + 0], bf[ni * 2 + 0], acc[f][ni], 0, 0, 0);
        acc[f][ni] = __builtin_amdgcn_mfma_f32_16x16x32_bf16(af[f * 2 + 1], bf[ni * 2 + 1], acc[f][ni], 0, 0, 0);
      }
    }
    __builtin_amdgcn_s_setprio(0);
    asm volatile("s_waitcnt lgkmcnt(4)" ::: "memory");
    __builtin_amdgcn_sched_barrier(0);
    __builtin_amdgcn_s_setprio(1);
#pragma unroll
    for (int ni = 0; ni < 4; ++ni) {
#pragma unroll
      for (int f = 4; f < 6; ++f) {
        acc[f][ni] = __builtin_amdgcn_mfma_f32_16x16x32_bf16(af[f * 2 + 0], bf[ni * 2 + 0], acc[f][ni], 0, 0, 0);
        acc[f][ni] = __builtin_amdgcn_mfma_f32_16x16x32_bf16(af[f * 2 + 1], bf[ni * 2 + 1], acc[f][ni], 0, 0, 0);
      }
    }
    __builtin_amdgcn_s_setprio(0);
    asm volatile("s_waitcnt lgkmcnt(0)" ::: "memory");
    __builtin_amdgcn_sched_barrier(0);
    __builtin_amdgcn_s_setprio(1);
#pragma unroll
    for (int ni = 0; ni < 4; ++ni) {
#pragma unroll
      for (int f = 6; f < 8; ++f) {
        acc[f][ni] = __builtin_amdgcn_mfma_f32_16x16x32_bf16(af[f * 2 + 0], bf[ni * 2 + 0], acc[f][ni], 0, 0, 0);
        acc[f][ni] = __builtin_amdgcn_mfma_f32_16x16x32_bf16(af[f * 2 + 1], bf[ni * 2 + 1], acc[f][ni], 0, 0, 0);
      }
    }
    __builtin_amdgcn_s_setprio(0);
    __builtin_amdgcn_sched_barrier(0);

    // stage tile t+2 into the buffer just consumed; certify t+1's stages
    stgA(Ad, t + 2, 0); stgA(Ad, t + 2, 1);
    stgB(Bd, t + 2, 0); stgB(Bd, t + 2, 1);
    asm volatile("s_waitcnt vmcnt(8)" ::: "memory");
    rawbar();
  }

  // drain everything before epilogue
  asm volatile("s_waitcnt vmcnt(0) lgkmcnt(0)" ::: "memory");
  __builtin_amdgcn_sched_barrier(0);

  // epilogue: C/D map col=lane&15, row=(lane>>4)*4+reg
  int rr = lane & 15, cr = (lane >> 4) * 4;
#pragma unroll
  for (int f = 0; f < 8; ++f) {
#pragma unroll
    for (int ni = 0; ni < 4; ++ni) {
      int gc = n0 + wn * 64 + ni * 16 + rr;
      float bv = bias[gc];
#pragma unroll
      for (int rg = 0; rg < 4; ++rg) {
        int gr = m0 + wm * 128 + f * 16 + cr + rg;
        float v = acc[f][ni][rg] + bv;
        if constexpr (EPI == 1) {
          ((unsigned short*)Cv)[(size_t)gr * N + gc] = f2bf(gelu_erf(v));
        } else {
          ((float*)Cv)[(size_t)gr * N + gc] = v;
        }
      }
    }
  }
}

// ---------------- per-chunk K^T V and K sums ----------------
__global__ __launch_bounds__(256) void chunk_sums(
    const float* __restrict__ QKV, float* __restrict__ KVc, float* __restrict__ Ksum)
{
  __shared__ float Ks[64][68], Vs[64][68];
  int blk = blockIdx.x, t0 = blk * 64, tid = threadIdx.x;
#pragma unroll
  for (int i = 0; i < 4; ++i) {
    int f = tid + i * 256;
    int r = f >> 4, c4 = (f & 15) * 4;
    const float* s = QKV + (size_t)(t0 + r) * 256;
    f4 k = *(const f4*)(s + 64 + c4);
    f4 v = *(const f4*)(s + 128 + c4);
#pragma unroll
    for (int e = 0; e < 4; ++e) { Ks[r][c4 + e] = elu1(k[e]); Vs[r][c4 + e] = v[e]; }
  }
  __syncthreads();
  int i0 = tid >> 2, jb = (tid & 3) * 16;
  f4 a0 = {0,0,0,0}, a1 = {0,0,0,0}, a2 = {0,0,0,0}, a3 = {0,0,0,0};
  for (int t = 0; t < 64; ++t) {
    float kk = Ks[t][i0];
    a0 += kk * (*(const f4*)&Vs[t][jb]);
    a1 += kk * (*(const f4*)&Vs[t][jb + 4]);
    a2 += kk * (*(const f4*)&Vs[t][jb + 8]);
    a3 += kk * (*(const f4*)&Vs[t][jb + 12]);
  }
  float* d = KVc + (size_t)blk * 4096 + i0 * 64 + jb;
  *(f4*)(d) = a0; *(f4*)(d + 4) = a1; *(f4*)(d + 8) = a2; *(f4*)(d + 12) = a3;
  if (tid < 64) {
    float s = 0.f;
    for (int t = 0; t < 64; ++t) s += Ks[t][tid];
    Ksum[(size_t)blk * 64 + tid] = s;
  }
}

// ---------------- exclusive prefix of chunk states ----------------
__global__ __launch_bounds__(256) void prefix_state(
    const float* __restrict__ KVc, const float* __restrict__ Ksum,
    float* __restrict__ KVp, float* __restrict__ Ksump)
{
  int b = blockIdx.x >> 3, seg = blockIdx.x & 7;
  int e = seg * 512 + threadIdx.x * 2;
  f2 run = {0.f, 0.f};
#pragma unroll
  for (int c = 0; c < 32; ++c) {
    size_t base = ((size_t)b * 32 + c) * 4096 + e;
    *(f2*)(KVp + base) = run;
    run += *(const f2*)(KVc + base);
  }
  if (seg == 0 && threadIdx.x < 64) {
    float rs = 0.f; int i = threadIdx.x;
#pragma unroll
    for (int c = 0; c < 32; ++c) {
      size_t base = ((size_t)b * 32 + c) * 64 + i;
      Ksump[base] = rs;
      rs += Ksum[base];
    }
  }
}

// ---------------- per-chunk normalized attention coefficients ----------------
__global__ __launch_bounds__(256) void attn_ns(
    const float* __restrict__ QKV, const float* __restrict__ KVp,
    const float* __restrict__ Ksump, float* __restrict__ NsG)
{
  __shared__ float Qs[64][68], Ks[64][68], Vs[64][68], Ss[64][68], Ps[64][68];
  __shared__ float ksps[64];
  int blk = blockIdx.x, t0 = blk * 64, tid = threadIdx.x;
#pragma unroll
  for (int i = 0; i < 4; ++i) {
    int f = tid + i * 256;
    int r = f >> 4, c4 = (f & 15) * 4;
    const float* s = QKV + (size_t)(t0 + r) * 256;
    f4 q = *(const f4*)(s + c4);
    f4 k = *(const f4*)(s + 64 + c4);
    f4 v = *(const f4*)(s + 128 + c4);
    f4 p = *(const f4*)(KVp + (size_t)blk * 4096 + r * 64 + c4);
#pragma unroll
    for (int e = 0; e < 4; ++e) {
      Qs[r][c4 + e] = elu1(q[e]); Ks[r][c4 + e] = elu1(k[e]);
      Vs[r][c4 + e] = v[e];       Ps[r][c4 + e] = p[e];
    }
  }
  if (tid < 64) ksps[tid] = Ksump[(size_t)blk * 64 + tid];
  __syncthreads();
  int tq = tid >> 2, jb = (tid & 3) * 16;
#pragma unroll
  for (int jj = 0; jj < 16; ++jj) {
    int tk = jb + jj;
    float s = 0.f;
    if (tk <= tq) {
#pragma unroll
      for (int k4 = 0; k4 < 16; ++k4) {
        f4 q = *(const f4*)&Qs[tq][k4 * 4];
        f4 k = *(const f4*)&Ks[tk][k4 * 4];
        s += q[0] * k[0] + q[1] * k[1] + q[2] * k[2] + q[3] * k[3];
      }
    }
    Ss[tq][tk] = s;
  }
  __syncthreads();
  f4 a0 = {0,0,0,0}, a1 = {0,0,0,0}, a2 = {0,0,0,0}, a3 = {0,0,0,0};
  for (int t = 0; t < 64; ++t) {
    float s = Ss[tq][t];
    a0 += s * (*(const f4*)&Vs[t][jb]);
    a1 += s * (*(const f4*)&Vs[t][jb + 4]);
    a2 += s * (*(const f4*)&Vs[t][jb + 8]);
    a3 += s * (*(const f4*)&Vs[t][jb + 12]);
  }
  for (int k = 0; k < 64; ++k) {
    float q = Qs[tq][k];
    a0 += q * (*(const f4*)&Ps[k][jb]);
    a1 += q * (*(const f4*)&Ps[k][jb + 4]);
    a2 += q * (*(const f4*)&Ps[k][jb + 8]);
    a3 += q * (*(const f4*)&Ps[k][jb + 12]);
  }
  float den = 0.f;
  for (int t = 0; t < 64; ++t) den += Ss[tq][t];
  for (int k = 0; k < 64; ++k) den += Qs[tq][k] * ksps[k];
  float inv = 1.f / (den + 1e-6f);
  float* d = NsG + (size_t)(t0 + tq) * 64 + jb;
  *(f4*)(d)      = a0 * inv;
  *(f4*)(d + 4)  = a1 * inv;
  *(f4*)(d + 8)  = a2 * inv;
  *(f4*)(d + 12) = a3 * inv;
}

// ---------------- attn @ Wo + residual into X ----------------
__global__ __launch_bounds__(256) void attn_apply(
    const float* __restrict__ NsG, const float* __restrict__ Wo, float* __restrict__ X)
{
  __shared__ float Ns[64][68];
  __shared__ float Wt[64][260];
  int chunk = blockIdx.x >> 2, dg = blockIdx.x & 3;
  int t0 = chunk * 64, d0 = dg * 256, tid = threadIdx.x;
#pragma unroll
  for (int i = 0; i < 4; ++i) {
    int f = tid + i * 256;
    int r = f >> 4, c4 = (f & 15) * 4;
    *(f4*)&Ns[r][c4] = *(const f4*)(NsG + (size_t)(t0 + r) * 64 + c4);
  }
#pragma unroll
  for (int i = 0; i < 16; ++i) {
    int f = tid + i * 256;
    int r = f >> 6, c4 = (f & 63) * 4;
    *(f4*)&Wt[r][c4] = *(const f4*)(Wo + (size_t)r * 1024 + d0 + c4);
  }
  __syncthreads();
  int w = tid >> 6, lane = tid & 63;
  for (int ts = 0; ts < 16; ++ts) {
    int t = w * 16 + ts;
    float a0 = 0.f, a1 = 0.f, a2 = 0.f, a3 = 0.f;
#pragma unroll
    for (int j = 0; j < 64; ++j) {
      float nv = Ns[t][j];
      a0 += nv * Wt[j][lane];
      a1 += nv * Wt[j][64 + lane];
      a2 += nv * Wt[j][128 + lane];
      a3 += nv * Wt[j][192 + lane];
    }
    size_t o = (size_t)(t0 + t) * 1024 + d0 + lane;
    X[o]       += a0;
    X[o + 64]  += a1;
    X[o + 128] += a2;
    X[o + 192] += a3;
  }
}

// ---------------- layernorm over D=1024, writes f32 + bf16 ----------------
__global__ __launch_bounds__(256) void layernorm_kernel(
    float* __restrict__ X, unsigned short* __restrict__ XB,
    const float* __restrict__ g, const float* __restrict__ b)
{
  int t = blockIdx.x * 4 + (threadIdx.x >> 6);
  int lane = threadIdx.x & 63;
  float* row = X + (size_t)t * 1024;
  f4 v[4];
  float s = 0.f, s2 = 0.f;
#pragma unroll
  for (int i = 0; i < 4; ++i) {
    v[i] = *(const f4*)(row + (i * 64 + lane) * 4);
#pragma unroll
    for (int e = 0; e < 4; ++e) { s += v[i][e]; s2 += v[i][e] * v[i][e]; }
  }
#pragma unroll
  for (int off = 32; off > 0; off >>= 1) {
    s  += __shfl_xor(s, off, 64);
    s2 += __shfl_xor(s2, off, 64);
  }
  float mean = s * (1.f / 1024.f);
  float var = s2 * (1.f / 1024.f) - mean * mean;
  float rstd = rsqrtf(var + 1e-5f);
#pragma unroll
  for (int i = 0; i < 4; ++i) {
    int d = (i * 64 + lane) * 4;
    f4 gv = *(const f4*)(g + d);
    f4 bv = *(const f4*)(b + d);
    f4 y;
#pragma unroll
    for (int e = 0; e < 4; ++e) y[e] = (v[i][e] - mean) * rstd * gv[e] + bv[e];
    *(f4*)(row + d) = y;
    us4 o = { f2bf(y[0]), f2bf(y[1]), f2bf(y[2]), f2bf(y[3]) };
    *(us4*)(XB + (size_t)t * 1024 + d) = o;
  }
}

extern "C" void kernel_launch(void* const* d_in, const int* in_sizes, int n_in,
                              void* d_out, int out_size, void* d_ws, size_t ws_size,
                              hipStream_t stream) {
  (void)in_sizes; (void)n_in; (void)out_size;
  const int*   idx = (const int*)d_in[0];
  const float* tok = (const float*)d_in[1];
  const float* pos = (const float*)d_in[2];
  const float* Wq  = (const float*)d_in[3];
  const float* Wk  = (const float*)d_in[4];
  const float* Wv  = (const float*)d_in[5];
  const float* Wo  = (const float*)d_in[6];
  const float* ng  = (const float*)d_in[7];
  const float* nb  = (const float*)d_in[8];
  const float* ong = (const float*)d_in[9];
  const float* onb = (const float*)d_in[10];
  const float* W1  = (const float*)d_in[11];
  const float* b1  = (const float*)d_in[12];
  const float* W2  = (const float*)d_in[13];
  const float* b2  = (const float*)d_in[14];
  float* out = (float*)d_out;
  char* ws = (char*)d_ws;

  float* X            = (float*)(ws + 0);
  unsigned short* XB  = (unsigned short*)(ws + 16777216);
  unsigned short* QT0 = (unsigned short*)(ws + 25165824);
  unsigned short* QT1 = (unsigned short*)(ws + 25690112);
  float* QKVB         = (float*)(ws + 26214400);
  float* KVC          = (float*)(ws + 30408704);
  float* KSUM         = (float*)(ws + 31457280);
  float* KVP          = (float*)(ws + 31490048);
  float* KSP          = (float*)(ws + 32538624);
  unsigned short* W1T = (unsigned short*)(ws + 32571392);
  unsigned short* H   = (unsigned short*)(ws + 40960000);
  unsigned short* W2T = (unsigned short*)(ws + 74514432);
  float* NSG = KVC;  // reuse: KVC dead after prefix_state
  bool bigws = ws_size >= 336658432ull;

  hipMemsetAsync(QT0, 0, 524288, stream);
  hipMemsetAsync(QT1, 0, 524288, stream);
  transpose_cvt<<<dim3(16, 1), 256, 0, stream>>>(Wq,          QT0,              64, 1024);
  transpose_cvt<<<dim3(16, 1), 256, 0, stream>>>(Wk,          QT0 + 64 * 1024,  64, 1024);
  transpose_cvt<<<dim3(16, 1), 256, 0, stream>>>(Wv,          QT0 + 128 * 1024, 64, 1024);
  transpose_cvt<<<dim3(16, 1), 256, 0, stream>>>(Wq + 65536,  QT1,              64, 1024);
  transpose_cvt<<<dim3(16, 1), 256, 0, stream>>>(Wk + 65536,  QT1 + 64 * 1024,  64, 1024);
  transpose_cvt<<<dim3(16, 1), 256, 0, stream>>>(Wv + 65536,  QT1 + 128 * 1024, 64, 1024);
  transpose_cvt<<<dim3(16, 64), 256, 0, stream>>>(W1, W1T, 4096, 1024);
  if (bigws)
    transpose_cvt<<<dim3(64, 500), 256, 0, stream>>>(W2, W2T, 32000, 4096);

  embed_kernel<<<4096, 256, 0, stream>>>(idx, tok, pos, X, XB);

  for (int layer = 0; layer < 2; ++layer) {
    const unsigned short* QT = layer ? QT1 : QT0;
    gemm_bt<0, 0><<<64, 256, 0, stream>>>(XB, QT, nullptr, nullptr, QKVB, 4096, 256, 1024, 32);
    chunk_sums<<<64, 256, 0, stream>>>(QKVB, KVC, KSUM);
    prefix_state<<<16, 256, 0, stream>>>(KVC, KSUM, KVP, KSP);
    attn_ns<<<64, 256, 0, stream>>>(QKVB, KVP, KSP, NSG);
    attn_apply<<<256, 256, 0, stream>>>(NSG, Wo + (size_t)layer * 65536, X);
    layernorm_kernel<<<1024, 256, 0, stream>>>(X, XB, ng + layer * 1024, nb + layer * 1024);
  }
  layernorm_kernel<<<1024, 256, 0, stream>>>(X, XB, ong, onb);

  // W1: proven 128^2 kernel at 4 blocks/CU (r1 config) — ~55us
  gemm_bt<1, 0><<<1024, 256, 0, stream>>>(XB, W1T, nullptr, b1, H, 4096, 4096, 1024, 32);
  if (bigws)
    gemm2<2><<<2000, 512, 0, stream>>>(H, W2T, b2, out, 4096, 32000, 4096, 16);
  else
    gemm_bt<2, 1><<<8000, 256, 0, stream>>>(H, nullptr, W2, b2, out, 4096, 32000, 4096, 32);
}